// Round 5
// baseline (1942.233 us; speedup 1.0000x reference)
//
#include <hip/hip_runtime.h>

#define NN 20000
#define NE 200000
#define NG 512

__device__ __forceinline__ int lowerb(const int* a, int n, int v){
  int lo=0, hi=n;
  while(lo<hi){ int m=(lo+hi)>>1; if(a[m]<v) lo=m+1; else hi=m; }
  return lo;
}

// async global->LDS copy, 16B per lane. LDS dest must be linear in lane order
// (wave-uniform base + lane*16). AUX=2 sets NT (non-temporal / evict-first in L2):
// used for the H stream, which is read exactly once per split-dispatch, so it
// must not evict the reused x/y gather working set (round-4 cache cliff).
template<int AUX>
__device__ __forceinline__ void gload_lds16(const float4* g, float4* l){
  __builtin_amdgcn_global_load_lds(
    (const __attribute__((address_space(1))) void*)(g),
    (__attribute__((address_space(3))) void*)(l), 16, 0, AUX);
}

// ---------------- counting sort by tgt -> CSR ----------------
__global__ void k_count(const int* __restrict__ tgt, int* __restrict__ cnt){
  int e = blockIdx.x*blockDim.x + threadIdx.x;
  if(e<NE) atomicAdd(&cnt[tgt[e]], 1);
}

__global__ void k_scan(const int* __restrict__ cnt, int* __restrict__ row_start){
  __shared__ int part[1024];
  int t = threadIdx.x;
  const int CH = (NN + 1023)/1024; // 20
  int i0 = t*CH;
  int s = 0;
  for(int j=0;j<CH;j++){ int i=i0+j; if(i<NN) s += cnt[i]; }
  part[t] = s; __syncthreads();
  for(int d=1; d<1024; d<<=1){
    int v = (t>=d) ? part[t-d] : 0;
    __syncthreads();
    part[t] += v;
    __syncthreads();
  }
  int run = (t==0) ? 0 : part[t-1];
  for(int j=0;j<CH;j++){ int i=i0+j; if(i<NN){ row_start[i]=run; run += cnt[i]; } }
  if(t==0) row_start[NN] = part[1023];
}

// place edges in CSR order AND gather edge_attr to CSR order (fused)
__global__ void k_place(const int* __restrict__ src, const int* __restrict__ tgt,
                        const float* __restrict__ ea,
                        const int* __restrict__ row_start, int* __restrict__ cur,
                        int* __restrict__ es_src, float* __restrict__ es_ea){
  int e = blockIdx.x*blockDim.x + threadIdx.x;
  if(e>=NE) return;
  int n = tgt[e];
  int pos = row_start[n] + atomicAdd(&cur[n],1);
  es_src[pos] = src[e];
  const float4* s = (const float4*)ea + (size_t)e*4;
  float4* d = (float4*)es_ea + (size_t)pos*4;
  d[0]=s[0]; d[1]=s[1]; d[2]=s[2]; d[3]=s[3];
}

// ---------------- H = relu(es_ea @ W1 + b1), CSR-ordered, E x 128 ----------------
__launch_bounds__(256, 4)
__global__ void k_hmlp(const float* __restrict__ es_ea, const float* __restrict__ W1,
                       const float* __restrict__ b1, float* __restrict__ H){
  const int pc = threadIdx.x & 31, er = threadIdx.x >> 5;
  const size_t e = (size_t)blockIdx.x*8 + er;
  float4 w1v[16];
  #pragma unroll
  for(int i=0;i<16;i++) w1v[i] = *(const float4*)&W1[i*128 + pc*4];
  float4 hv = *(const float4*)&b1[pc*4];
  float eav[16];
  const float4* eap = (const float4*)(es_ea + e*16);
  #pragma unroll
  for(int q=0;q<4;q++){
    float4 v = eap[q];
    eav[q*4+0]=v.x; eav[q*4+1]=v.y; eav[q*4+2]=v.z; eav[q*4+3]=v.w;
  }
  #pragma unroll
  for(int i=0;i<16;i++){
    hv.x += eav[i]*w1v[i].x;
    hv.y += eav[i]*w1v[i].y;
    hv.z += eav[i]*w1v[i].z;
    hv.w += eav[i]*w1v[i].w;
  }
  hv.x = fmaxf(hv.x,0.f); hv.y = fmaxf(hv.y,0.f);
  hv.z = fmaxf(hv.z,0.f); hv.w = fmaxf(hv.w,0.f);
  *(float4*)&H[e*128 + pc*4] = hv;
}

// ---------------- xbar[n,i] = mean over in-edges of x[src,i] ----------------
template<int IC>
__global__ void k_xbar(const float* __restrict__ x, const int* __restrict__ es_src,
                       const int* __restrict__ row_start, float* __restrict__ xbar){
  constexpr int TI = IC/16;
  const int wid = threadIdx.x>>6, lane = threadIdx.x&63;
  const int n = blockIdx.x*4 + wid;
  const int eg = lane>>4, ig = lane&15;
  const int a = row_start[n], b = row_start[n+1];
  float s[TI];
  #pragma unroll
  for(int u=0;u<TI;u++) s[u]=0.f;
  for(int e=a+eg; e<b; e+=4){
    int sn = es_src[e];
    #pragma unroll
    for(int u=0;u<TI;u++) s[u] += x[(size_t)sn*IC + ig*TI + u];
  }
  #pragma unroll
  for(int u=0;u<TI;u++){
    s[u] += __shfl_xor(s[u], 16, 64);
    s[u] += __shfl_xor(s[u], 32, 64);
  }
  if(eg==0){
    float dinv = 1.f/fmaxf((float)(b-a), 1.f);
    #pragma unroll
    for(int u=0;u<TI;u++) xbar[(size_t)n*IC + ig*TI + u] = s[u]*dinv;
  }
}

// ---------------- fused NNConv layer: wave-private scatter + coalesced k-split GEMM ----------------
// Round 5: occupancy via 512-thread blocks (8 waves) at UNCHANGED BN=8 tile / KS /
// grid / traffic. Round 4's BN=4 retile doubled occupancy but collapsed (dur 2.2x):
// FETCH 101->304MB (y1 gather cache-cliff: doubled stream rate evicts the 3.84MB
// working set from 4MB/XCD L2) and WRITE 40->638MB @ VGPR 40 (suspected allocator
// scratch under (256,6)). This version keeps the round-3-verified tile and doubles
// waves/CU instead: LDS ~52KB -> 3 blocks x 8 waves = 24 waves/CU (75%) for L2,
// 4 blocks for L1/L3. H staging loads are NT (evict-first) to protect the gather.
// Scatter: each of 8 waves owns 1 node; lane=(pw,iw); acc[PP][TI] <= 48 floats.
// GEMM: k-range split 8 ways across waves; wave pairs (w, w+4) combine via LDS pad
// + one barrier so part slice count / k_epi stay exactly as round 3.
// GEMM W2 ping-pong (round-2 win) kept; S reads in-iteration (round-1 spill lesson:
// FETCH~101MB / WRITE~40MB is the no-spill check).
template<int IC, int OC, int PLEN, int KS, int BN, int PP, int TI, int OQ, int TO, bool PF, int EB>
__launch_bounds__(512, 6)
__global__ void k_layer(const float* __restrict__ x_in, const float* __restrict__ H,
                        const int* __restrict__ es_src, const int* __restrict__ row_start,
                        const float* __restrict__ W2, float* __restrict__ part)
{
  constexpr int K    = PLEN*IC;
  constexpr int HV4  = PLEN/4;
  constexpr int XV   = IC/4;
  constexpr int NIW  = IC/TI;
  constexpr int NPW  = PLEN/PP;
  constexpr int KQL  = 64/OQ;
  constexpr int TSPL = 8*KQL;            // 8 waves cover the k-range
  constexpr int J    = (K/4)/TSPL;
  constexpr int NH4  = (EB*HV4)/512;     // hb staging chunks (exact)
  constexpr int NX4  = (EB*XV + 511)/512;// xs staging chunks
  static_assert(BN==8, "one node per wave");
  static_assert(NPW*NIW==64, "wave tile covers 64 lanes");
  static_assert(PP*TI <= 48, "spill-safe accumulator");
  static_assert(EB*(PLEN+IC) <= BN*K, "staging alias fits in S");
  static_assert((EB*HV4)%512==0, "hb tail must not round into xs region");
  static_assert(EB*PLEN/4 + NX4*512 <= BN*K/4, "xs tail rounding stays inside S");
  static_assert(OQ*TO==OC && (K/4)%TSPL==0, "gemm tiling");
  static_assert(J%2==0, "ping-pong needs even J");

  __shared__ __align__(16) float S[BN*K];
  __shared__ float pad[4*BN*OC];         // lo-wave GEMM partials
  __shared__ int rs_s[BN+1], ro[BN+1];

  float* hb = S;                 // EB*PLEN staged H slice
  float* xs = S + EB*PLEN;       // EB*IC staged x[src]

  const int tid = threadIdx.x;
  const int wid = tid>>6, lane = tid&63;
  const int split = blockIdx.x % KS;
  const int nb = blockIdx.x / KS;
  const int n0 = nb*BN;
  const int p04 = split*HV4;

  if(tid<=BN) rs_s[tid] = row_start[n0+tid];
  __syncthreads();
  const int estart = rs_s[0], eend = rs_s[BN];

  const int pw = lane / NIW;
  const int iw = lane - pw*NIW;

  float acc[PP][TI];
  #pragma unroll
  for(int p=0;p<PP;p++)
    #pragma unroll
    for(int u=0;u<TI;u++) acc[p][u]=0.f;

  const float4* H4 = (const float4*)H;
  const float4* x4 = (const float4*)x_in;

  for(int bstart=estart; bstart<eend; bstart+=EB){
    const int ebc = min(EB, eend-bstart);
    if(tid<=BN){ int v = rs_s[tid]-bstart; ro[tid] = min(max(v,0), ebc); }
    const int hb_lim = ebc*HV4, xs_lim = ebc*XV;
    // pre-load gather indices (independent loads, issued together)
    int sn_r[NX4];
    #pragma unroll
    for(int c=0;c<NX4;c++){
      int jc = min(tid + c*512, xs_lim-1);
      sn_r[c] = es_src[bstart + jc/XV];
    }
    // async H slice -> hb (NT: single-use stream, don't evict gather set)
    #pragma unroll
    for(int c=0;c<NH4;c++){
      int j = tid + c*512;
      int jc = min(j, hb_lim-1);
      int e = jc/HV4, q = jc - e*HV4;
      gload_lds16<2>(H4 + (size_t)(bstart+e)*32 + p04 + q, ((float4*)hb) + j);
    }
    // async x[src] -> xs (temporal: reused across blocks, keep cached)
    #pragma unroll
    for(int c=0;c<NX4;c++){
      int j = tid + c*512;
      int jc = min(j, xs_lim-1);
      int q = jc - (jc/XV)*XV;
      gload_lds16<0>(x4 + (size_t)sn_r[c]*XV + q, ((float4*)xs) + j);
    }
    __syncthreads();   // drains vmcnt (global_load_lds tracked there)
    // wave-private scatter: wave wid owns node n0+wid
    {
      const int a = ro[wid], b = ro[wid+1];
      if constexpr (PF){
        if(a<b){
          float hv[PP], xv[TI];
          #pragma unroll
          for(int p=0;p<PP;p++) hv[p] = hb[a*PLEN + pw*PP + p];
          #pragma unroll
          for(int u=0;u<TI;u++) xv[u] = xs[a*IC + iw*TI + u];
          for(int e=a; e<b; e++){
            float hn[PP], xn[TI];
            if(e+1<b){
              #pragma unroll
              for(int p=0;p<PP;p++) hn[p] = hb[(e+1)*PLEN + pw*PP + p];
              #pragma unroll
              for(int u=0;u<TI;u++) xn[u] = xs[(e+1)*IC + iw*TI + u];
            }
            #pragma unroll
            for(int p=0;p<PP;p++)
              #pragma unroll
              for(int u=0;u<TI;u++) acc[p][u] += hv[p]*xv[u];
            #pragma unroll
            for(int p=0;p<PP;p++) hv[p]=hn[p];
            #pragma unroll
            for(int u=0;u<TI;u++) xv[u]=xn[u];
          }
        }
      } else {
        for(int e=a; e<b; e++){
          float hv[PP];
          #pragma unroll
          for(int p=0;p<PP;p++) hv[p] = hb[e*PLEN + pw*PP + p];
          float xv[TI];
          #pragma unroll
          for(int u=0;u<TI;u++) xv[u] = xs[e*IC + iw*TI + u];
          #pragma unroll
          for(int p=0;p<PP;p++)
            #pragma unroll
            for(int u=0;u<TI;u++) acc[p][u] += hv[p]*xv[u];
        }
      }
    }
    __syncthreads();
  }

  // dump scaled S (staging area dead); wave wid owns node row wid
  {
    const float dv = 1.f/fmaxf((float)(rs_s[wid+1]-rs_s[wid]), 1.f);
    #pragma unroll
    for(int p=0;p<PP;p++)
      #pragma unroll
      for(int u=0;u<TI;u++)
        S[(wid*PLEN + pw*PP + p)*IC + iw*TI + u] = acc[p][u]*dv;
  }

  // ---- GEMM: slice[n][o] partial over this wave's k-range; coalesced W2 ----
  const int oq  = lane % OQ;
  const int kql = lane / OQ;
  const int o0  = oq*TO;
  const float* W2b = W2 + (size_t)split*K*OC + o0;

  auto LOADW = [&](int j, float (&wv)[4][TO]){
    const int k4 = j*TSPL + wid*KQL + kql;
    #pragma unroll
    for(int r=0;r<4;r++){
      const float* wr = W2b + (size_t)(4*k4+r)*OC;
      if constexpr (TO==4){
        float4 a=*(const float4*)wr;
        wv[r][0]=a.x; wv[r][1]=a.y; wv[r][2]=a.z; wv[r][3]=a.w;
      } else if constexpr (TO==3){
        wv[r][0]=wr[0]; wv[r][1]=wr[1]; wv[r][2]=wr[2];
      } else {
        float2 a=*(const float2*)wr;
        wv[r][0]=a.x; wv[r][1]=a.y;
      }
    }
  };

  float outp[BN][TO];
  #pragma unroll
  for(int n=0;n<BN;n++)
    #pragma unroll
    for(int t=0;t<TO;t++) outp[n][t]=0.f;

  float wvA[4][TO], wvB[4][TO];
  LOADW(0, wvA);          // W2 j=0 in flight across the barrier (independent of S)
  __syncthreads();        // S visible to all waves

  #pragma unroll 1
  for(int j=0;j<J;j+=2){
    LOADW(j+1, wvB);      // prefetch while FMAs on wvA run
    {
      const int k4 = j*TSPL + wid*KQL + kql;
      #pragma unroll
      for(int n=0;n<BN;n++){
        float4 sv = *(const float4*)&S[n*K + 4*k4];
        #pragma unroll
        for(int t=0;t<TO;t++)
          outp[n][t] += sv.x*wvA[0][t] + sv.y*wvA[1][t] + sv.z*wvA[2][t] + sv.w*wvA[3][t];
      }
    }
    if(j+2<J) LOADW(j+2, wvA);   // prefetch while FMAs on wvB run
    {
      const int k4 = (j+1)*TSPL + wid*KQL + kql;
      #pragma unroll
      for(int n=0;n<BN;n++){
        float4 sv = *(const float4*)&S[n*K + 4*k4];
        #pragma unroll
        for(int t=0;t<TO;t++)
          outp[n][t] += sv.x*wvB[0][t] + sv.y*wvB[1][t] + sv.z*wvB[2][t] + sv.w*wvB[3][t];
      }
    }
  }

  // intra-wave reduce over kql lanes (masks OQ..32)
  #pragma unroll
  for(int m=OQ; m<64; m<<=1)
    #pragma unroll
    for(int n=0;n<BN;n++)
      #pragma unroll
      for(int t=0;t<TO;t++) outp[n][t] += __shfl_xor(outp[n][t], m, 64);

  // wave-pair combine: waves 0-3 publish, waves 4-7 add + store slice split*4+(wid-4)
  const int widl = wid & 3;
  if(wid<4 && kql==0){
    #pragma unroll
    for(int n=0;n<BN;n++)
      #pragma unroll
      for(int t=0;t<TO;t++) pad[(widl*BN+n)*OC + o0 + t] = outp[n][t];
  }
  __syncthreads();
  if(wid>=4 && kql==0){
    float* slice = part + (size_t)(split*4+widl)*NN*OC;
    #pragma unroll
    for(int n=0;n<BN;n++){
      #pragma unroll
      for(int t=0;t<TO;t++) outp[n][t] += pad[(widl*BN+n)*OC + o0 + t];
      float* dst = slice + (size_t)(n0+n)*OC + o0;
      if constexpr (TO==4){
        *(float4*)dst = make_float4(outp[n][0],outp[n][1],outp[n][2],outp[n][3]);
      } else if constexpr (TO==3){
        dst[0]=outp[n][0]; dst[1]=outp[n][1]; dst[2]=outp[n][2];
      } else {
        *(float2*)dst = make_float2(outp[n][0],outp[n][1]);
      }
    }
  }
}

// ---------------- epilogue: y = relu(sum_s part[s] + x@root + xbar@b2 + bias) ----------------
template<int IC, int OC, int SL>
__global__ void k_epi(const float* __restrict__ part, const float* __restrict__ x,
                      const float* __restrict__ xbar,
                      const float* __restrict__ root, const float* __restrict__ b2,
                      const float* __restrict__ bias, float* __restrict__ y)
{
  int idx = blockIdx.x*256 + threadIdx.x;
  if(idx >= NN*OC) return;
  int n = idx/OC, o = idx - n*OC;
  float v = bias[o];
  #pragma unroll
  for(int s=0;s<SL;s++) v += part[(size_t)s*NN*OC + idx];
  #pragma unroll
  for(int i=0;i<IC;i++) v += x[(size_t)n*IC+i]*root[i*OC+o];
  #pragma unroll
  for(int i=0;i<IC;i++) v += xbar[(size_t)n*IC+i]*b2[i*OC+o];
  y[idx] = fmaxf(v, 0.f);
}

// ---------------- set2set (2 steps) + final MLP, one wave per graph ----------------
__global__ void k_s2s(const float* __restrict__ xg, const int* __restrict__ batch,
  const float* __restrict__ Wih, const float* __restrict__ Whh,
  const float* __restrict__ bih, const float* __restrict__ bhh,
  const float* __restrict__ l1W, const float* __restrict__ l1b,
  const float* __restrict__ l2W, const float* __restrict__ l2b,
  const float* __restrict__ lfW, const float* __restrict__ lfb,
  float* __restrict__ out)
{
  int g = blockIdx.x, lane = threadIdx.x;
  __shared__ float hs[16], cs[16], qs[32], gs[64], rs[16];
  int r0 = lowerb(batch, NN, g);
  int r1 = lowerb(batch, NN, g+1);
  if(lane<16){ hs[lane]=0.f; cs[lane]=0.f; }
  if(lane<32) qs[lane]=0.f;
  __syncthreads();
  for(int step=0; step<2; step++){
    float gate = bih[lane] + bhh[lane];
    for(int k=0;k<32;k++) gate += qs[k]*Wih[lane*32+k];
    for(int k=0;k<16;k++) gate += hs[k]*Whh[lane*16+k];
    gs[lane] = gate;
    __syncthreads();
    if(lane<16){
      float ig = 1.f/(1.f+expf(-gs[lane]));
      float fg = 1.f/(1.f+expf(-gs[lane+16]));
      float gg = tanhf(gs[lane+32]);
      float og = 1.f/(1.f+expf(-gs[lane+48]));
      float cn = fg*cs[lane] + ig*gg;
      cs[lane] = cn;
      hs[lane] = og*tanhf(cn);
    }
    __syncthreads();
    float m = -1e30f;
    for(int n=r0+lane; n<r1; n+=64){
      float e=0.f;
      for(int k=0;k<16;k++) e += xg[n*16+k]*hs[k];
      m = fmaxf(m, e);
    }
    for(int d=1; d<64; d<<=1) m = fmaxf(m, __shfl_xor(m, d));
    float ssum = 0.f;
    float racc[16];
    #pragma unroll
    for(int k=0;k<16;k++) racc[k]=0.f;
    for(int n=r0+lane; n<r1; n+=64){
      float e=0.f, xv[16];
      #pragma unroll
      for(int k=0;k<16;k++){ xv[k]=xg[n*16+k]; e += xv[k]*hs[k]; }
      float a = expf(e - m);
      ssum += a;
      #pragma unroll
      for(int k=0;k<16;k++) racc[k] += a*xv[k];
    }
    for(int d=1; d<64; d<<=1) ssum += __shfl_xor(ssum, d);
    #pragma unroll
    for(int k=0;k<16;k++)
      for(int d=1; d<64; d<<=1) racc[k] += __shfl_xor(racc[k], d);
    ssum = fmaxf(ssum, 1e-16f);
    if(lane==0){
      #pragma unroll
      for(int k=0;k<16;k++) rs[k] = racc[k]/ssum;
    }
    __syncthreads();
    if(lane<16){ qs[lane]=hs[lane]; qs[16+lane]=rs[lane]; }
    __syncthreads();
  }
  if(lane<16){
    float v = l1b[lane];
    for(int k=0;k<32;k++) v += qs[k]*l1W[k*16+lane];
    gs[lane] = fmaxf(v,0.f);
  }
  __syncthreads();
  if(lane<8){
    float v = l2b[lane];
    for(int k=0;k<16;k++) v += gs[k]*l2W[k*8+lane];
    gs[32+lane] = fmaxf(v,0.f);
  }
  __syncthreads();
  if(lane==0){
    float v = lfb[0];
    for(int k=0;k<8;k++) v += gs[32+k]*lfW[k];
    out[g] = v;
  }
}

extern "C" void kernel_launch(void* const* d_in, const int* in_sizes, int n_in,
                              void* d_out, int out_size, void* d_ws, size_t ws_size,
                              hipStream_t stream) {
  const float* x0   = (const float*)d_in[0];
  const int*   ei   = (const int*)d_in[1];
  const float* ea   = (const float*)d_in[2];
  const int*   batch= (const int*)d_in[3];
  const float* c1W1 = (const float*)d_in[4];  const float* c1b1 = (const float*)d_in[5];
  const float* c1W2 = (const float*)d_in[6];  const float* c1b2 = (const float*)d_in[7];
  const float* c1rt = (const float*)d_in[8];  const float* c1bs = (const float*)d_in[9];
  const float* c2W1 = (const float*)d_in[10]; const float* c2b1 = (const float*)d_in[11];
  const float* c2W2 = (const float*)d_in[12]; const float* c2b2 = (const float*)d_in[13];
  const float* c2rt = (const float*)d_in[14]; const float* c2bs = (const float*)d_in[15];
  const float* c3W1 = (const float*)d_in[16]; const float* c3b1 = (const float*)d_in[17];
  const float* c3W2 = (const float*)d_in[18]; const float* c3b2 = (const float*)d_in[19];
  const float* c3rt = (const float*)d_in[20]; const float* c3bs = (const float*)d_in[21];
  const float* Wih  = (const float*)d_in[22]; const float* Whh  = (const float*)d_in[23];
  const float* bih  = (const float*)d_in[24]; const float* bhh  = (const float*)d_in[25];
  const float* l1W  = (const float*)d_in[26]; const float* l1b  = (const float*)d_in[27];
  const float* l2W  = (const float*)d_in[28]; const float* l2b  = (const float*)d_in[29];
  const float* lfW  = (const float*)d_in[30]; const float* lfb  = (const float*)d_in[31];
  float* out = (float*)d_out;

  const int* src = ei;
  const int* tgt = ei + NE;

  // workspace carve (~190 MB)
  char* w = (char*)d_ws;
  auto carve = [&](size_t bytes)->void*{ void* p = (void*)w; w += (bytes + 255) & ~(size_t)255; return p; };
  int*   row_start = (int*)carve((NN+1)*sizeof(int));
  int*   cur       = (int*)carve(NN*sizeof(int));
  int*   es_src    = (int*)carve(NE*sizeof(int));
  float* es_ea     = (float*)carve((size_t)NE*16*sizeof(float));
  float* Hbuf      = (float*)carve((size_t)NE*128*sizeof(float));
  float* xbar      = (float*)carve((size_t)NN*48*sizeof(float));
  float* y1   = (float*)carve((size_t)NN*48*sizeof(float));
  float* y2   = (float*)carve((size_t)NN*32*sizeof(float));
  float* y3   = (float*)carve((size_t)NN*16*sizeof(float));
  float* part = (float*)carve((size_t)16*NN*48*sizeof(float)); // up to 16 slices

  // ---- CSR by tgt (+ fused ea gather)
  hipMemsetAsync(cur, 0, NN*sizeof(int), stream);
  k_count<<<(NE+255)/256, 256, 0, stream>>>(tgt, cur);
  k_scan<<<1, 1024, 0, stream>>>(cur, row_start);
  hipMemsetAsync(cur, 0, NN*sizeof(int), stream);
  k_place<<<(NE+255)/256, 256, 0, stream>>>(src, tgt, ea, row_start, cur, es_src, es_ea);

  // ---- layer 1: IC=16 OC=48 | PLEN=64 KS=2 BN=8 PP=4 TI=4 | OQ=16 TO=3 | PF on, EB=96 (8 slices)
  k_hmlp<<<NE/8, 256, 0, stream>>>(es_ea, c1W1, c1b1, Hbuf);
  k_xbar<16><<<NN/4, 256, 0, stream>>>(x0, es_src, row_start, xbar);
  k_layer<16,48,64,2,8,4,4,16,3,true,96><<<(NN/8)*2, 512, 0, stream>>>(x0, Hbuf, es_src, row_start, c1W2, part);
  k_epi<16,48,8><<<(NN*48+255)/256, 256, 0, stream>>>(part, x0, xbar, c1rt, c1b2, c1bs, y1);

  // ---- layer 2: IC=48 OC=32 | PLEN=32 KS=4 BN=8 PP=4 TI=6 | OQ=8 TO=4 | PF on, EB=128 (16 slices)
  k_hmlp<<<NE/8, 256, 0, stream>>>(es_ea, c2W1, c2b1, Hbuf);
  k_xbar<48><<<NN/4, 256, 0, stream>>>(y1, es_src, row_start, xbar);
  k_layer<48,32,32,4,8,4,6,8,4,true,128><<<(NN/8)*4, 512, 0, stream>>>(y1, Hbuf, es_src, row_start, c2W2, part);
  k_epi<48,32,16><<<(NN*32+255)/256, 256, 0, stream>>>(part, y1, xbar, c2rt, c2b2, c2bs, y2);

  // ---- layer 3: IC=32 OC=16 | PLEN=32 KS=4 BN=8 PP=4 TI=4 | OQ=4 TO=4 | PF on, EB=128 (16 slices)
  k_hmlp<<<NE/8, 256, 0, stream>>>(es_ea, c3W1, c3b1, Hbuf);
  k_xbar<32><<<NN/4, 256, 0, stream>>>(y2, es_src, row_start, xbar);
  k_layer<32,16,32,4,8,4,4,4,4,true,128><<<(NN/8)*4, 512, 0, stream>>>(y2, Hbuf, es_src, row_start, c3W2, part);
  k_epi<32,16,16><<<(NN*16+255)/256, 256, 0, stream>>>(part, y2, xbar, c3rt, c3b2, c3bs, y3);

  // ---- set2set + MLP head
  k_s2s<<<NG, 64, 0, stream>>>(y3, batch, Wih, Whh, bih, bhh, l1W, l1b, l2W, l2b, lfW, lfb, out);
}

// Round 6
// 1081.482 us; speedup vs baseline: 1.7959x; 1.7959x over previous
//
#include <hip/hip_runtime.h>

#define NN 20000
#define NE 200000
#define NG 512

__device__ __forceinline__ int lowerb(const int* a, int n, int v){
  int lo=0, hi=n;
  while(lo<hi){ int m=(lo+hi)>>1; if(a[m]<v) lo=m+1; else hi=m; }
  return lo;
}

// async global->LDS copy, 16B per lane. LDS dest must be linear in lane order
// (wave-uniform base + lane*16). AUX=2 sets NT (non-temporal / evict-first in L2):
// used for the H stream, which is read exactly once per split-dispatch, so it
// must not evict the reused x/y gather working set (round-4 cache cliff).
template<int AUX>
__device__ __forceinline__ void gload_lds16(const float4* g, float4* l){
  __builtin_amdgcn_global_load_lds(
    (const __attribute__((address_space(1))) void*)(g),
    (__attribute__((address_space(3))) void*)(l), 16, 0, AUX);
}

// ---------------- counting sort by tgt -> CSR ----------------
__global__ void k_count(const int* __restrict__ tgt, int* __restrict__ cnt){
  int e = blockIdx.x*blockDim.x + threadIdx.x;
  if(e<NE) atomicAdd(&cnt[tgt[e]], 1);
}

__global__ void k_scan(const int* __restrict__ cnt, int* __restrict__ row_start){
  __shared__ int part[1024];
  int t = threadIdx.x;
  const int CH = (NN + 1023)/1024; // 20
  int i0 = t*CH;
  int s = 0;
  for(int j=0;j<CH;j++){ int i=i0+j; if(i<NN) s += cnt[i]; }
  part[t] = s; __syncthreads();
  for(int d=1; d<1024; d<<=1){
    int v = (t>=d) ? part[t-d] : 0;
    __syncthreads();
    part[t] += v;
    __syncthreads();
  }
  int run = (t==0) ? 0 : part[t-1];
  for(int j=0;j<CH;j++){ int i=i0+j; if(i<NN){ row_start[i]=run; run += cnt[i]; } }
  if(t==0) row_start[NN] = part[1023];
}

// place edges in CSR order AND gather edge_attr to CSR order (fused)
__global__ void k_place(const int* __restrict__ src, const int* __restrict__ tgt,
                        const float* __restrict__ ea,
                        const int* __restrict__ row_start, int* __restrict__ cur,
                        int* __restrict__ es_src, float* __restrict__ es_ea){
  int e = blockIdx.x*blockDim.x + threadIdx.x;
  if(e>=NE) return;
  int n = tgt[e];
  int pos = row_start[n] + atomicAdd(&cur[n],1);
  es_src[pos] = src[e];
  const float4* s = (const float4*)ea + (size_t)e*4;
  float4* d = (float4*)es_ea + (size_t)pos*4;
  d[0]=s[0]; d[1]=s[1]; d[2]=s[2]; d[3]=s[3];
}

// ---------------- H = relu(es_ea @ W1 + b1), CSR-ordered, E x 128 ----------------
__launch_bounds__(256, 4)
__global__ void k_hmlp(const float* __restrict__ es_ea, const float* __restrict__ W1,
                       const float* __restrict__ b1, float* __restrict__ H){
  const int pc = threadIdx.x & 31, er = threadIdx.x >> 5;
  const size_t e = (size_t)blockIdx.x*8 + er;
  float4 w1v[16];
  #pragma unroll
  for(int i=0;i<16;i++) w1v[i] = *(const float4*)&W1[i*128 + pc*4];
  float4 hv = *(const float4*)&b1[pc*4];
  float eav[16];
  const float4* eap = (const float4*)(es_ea + e*16);
  #pragma unroll
  for(int q=0;q<4;q++){
    float4 v = eap[q];
    eav[q*4+0]=v.x; eav[q*4+1]=v.y; eav[q*4+2]=v.z; eav[q*4+3]=v.w;
  }
  #pragma unroll
  for(int i=0;i<16;i++){
    hv.x += eav[i]*w1v[i].x;
    hv.y += eav[i]*w1v[i].y;
    hv.z += eav[i]*w1v[i].z;
    hv.w += eav[i]*w1v[i].w;
  }
  hv.x = fmaxf(hv.x,0.f); hv.y = fmaxf(hv.y,0.f);
  hv.z = fmaxf(hv.z,0.f); hv.w = fmaxf(hv.w,0.f);
  *(float4*)&H[e*128 + pc*4] = hv;
}

// ---------------- xbar[n,i] = mean over in-edges of x[src,i] ----------------
template<int IC>
__global__ void k_xbar(const float* __restrict__ x, const int* __restrict__ es_src,
                       const int* __restrict__ row_start, float* __restrict__ xbar){
  constexpr int TI = IC/16;
  const int wid = threadIdx.x>>6, lane = threadIdx.x&63;
  const int n = blockIdx.x*4 + wid;
  const int eg = lane>>4, ig = lane&15;
  const int a = row_start[n], b = row_start[n+1];
  float s[TI];
  #pragma unroll
  for(int u=0;u<TI;u++) s[u]=0.f;
  for(int e=a+eg; e<b; e+=4){
    int sn = es_src[e];
    #pragma unroll
    for(int u=0;u<TI;u++) s[u] += x[(size_t)sn*IC + ig*TI + u];
  }
  #pragma unroll
  for(int u=0;u<TI;u++){
    s[u] += __shfl_xor(s[u], 16, 64);
    s[u] += __shfl_xor(s[u], 32, 64);
  }
  if(eg==0){
    float dinv = 1.f/fmaxf((float)(b-a), 1.f);
    #pragma unroll
    for(int u=0;u<TI;u++) xbar[(size_t)n*IC + ig*TI + u] = s[u]*dinv;
  }
}

// ---------------- fused NNConv layer: wave-private scatter + coalesced k-split GEMM ----------------
// Round 6: round-5 structure (8-wave blocks, BN=8 tile, traffic-invariant) with the
// allocator confound removed. Rounds 4+5 both set min-waves=6 and both produced
// VGPR=40 + GB-scale scratch spill (WRITE 40MB->3.2GB) -- the min-waves bound, not
// the structure, was the regression. Empirical toolchain rule: min-waves>=6 => VGPR
// squeezed to 40 + spill; min-waves<=3 => VGPR 68, clean. So: __launch_bounds__(512,2)
// (cap 256, allocator relaxed). Occupancy comes from LDS arithmetic instead:
// ~53.7KB/block -> 3 blocks x 8 waves = 24 waves/CU (75%) as long as VGPR<=85
// (expected ~70: round-3 inner code + trivial pad-combine).
// H staging loads NT (evict-first) to protect the x/y gather set (round-4 cliff).
// Scatter: each of 8 waves owns 1 node; lane=(pw,iw); acc[PP][TI] <= 48 floats.
// GEMM: k-range split 8 ways across waves; wave pairs (w, w+4) combine via LDS pad
// + one barrier so part slice count / k_epi stay exactly as round 3.
// GEMM W2 ping-pong (round-2 win) kept; S reads in-iteration (round-1 spill lesson).
// No-spill check every round: FETCH ~101MB, WRITE ~40MB, VGPR 60-85.
template<int IC, int OC, int PLEN, int KS, int BN, int PP, int TI, int OQ, int TO, bool PF, int EB>
__launch_bounds__(512, 2)
__global__ void k_layer(const float* __restrict__ x_in, const float* __restrict__ H,
                        const int* __restrict__ es_src, const int* __restrict__ row_start,
                        const float* __restrict__ W2, float* __restrict__ part)
{
  constexpr int K    = PLEN*IC;
  constexpr int HV4  = PLEN/4;
  constexpr int XV   = IC/4;
  constexpr int NIW  = IC/TI;
  constexpr int NPW  = PLEN/PP;
  constexpr int KQL  = 64/OQ;
  constexpr int TSPL = 8*KQL;            // 8 waves cover the k-range
  constexpr int J    = (K/4)/TSPL;
  constexpr int NH4  = (EB*HV4)/512;     // hb staging chunks (exact)
  constexpr int NX4  = (EB*XV + 511)/512;// xs staging chunks
  static_assert(BN==8, "one node per wave");
  static_assert(NPW*NIW==64, "wave tile covers 64 lanes");
  static_assert(PP*TI <= 48, "spill-safe accumulator");
  static_assert(EB*(PLEN+IC) <= BN*K, "staging alias fits in S");
  static_assert((EB*HV4)%512==0, "hb tail must not round into xs region");
  static_assert(EB*PLEN/4 + NX4*512 <= BN*K/4, "xs tail rounding stays inside S");
  static_assert(OQ*TO==OC && (K/4)%TSPL==0, "gemm tiling");
  static_assert(J%2==0, "ping-pong needs even J");

  __shared__ __align__(16) float S[BN*K];
  __shared__ float pad[4*BN*OC];         // lo-wave GEMM partials
  __shared__ int rs_s[BN+1], ro[BN+1];

  float* hb = S;                 // EB*PLEN staged H slice
  float* xs = S + EB*PLEN;       // EB*IC staged x[src]

  const int tid = threadIdx.x;
  const int wid = tid>>6, lane = tid&63;
  const int split = blockIdx.x % KS;
  const int nb = blockIdx.x / KS;
  const int n0 = nb*BN;
  const int p04 = split*HV4;

  if(tid<=BN) rs_s[tid] = row_start[n0+tid];
  __syncthreads();
  const int estart = rs_s[0], eend = rs_s[BN];

  const int pw = lane / NIW;
  const int iw = lane - pw*NIW;

  float acc[PP][TI];
  #pragma unroll
  for(int p=0;p<PP;p++)
    #pragma unroll
    for(int u=0;u<TI;u++) acc[p][u]=0.f;

  const float4* H4 = (const float4*)H;
  const float4* x4 = (const float4*)x_in;

  for(int bstart=estart; bstart<eend; bstart+=EB){
    const int ebc = min(EB, eend-bstart);
    if(tid<=BN){ int v = rs_s[tid]-bstart; ro[tid] = min(max(v,0), ebc); }
    const int hb_lim = ebc*HV4, xs_lim = ebc*XV;
    // pre-load gather indices (independent loads, issued together)
    int sn_r[NX4];
    #pragma unroll
    for(int c=0;c<NX4;c++){
      int jc = min(tid + c*512, xs_lim-1);
      sn_r[c] = es_src[bstart + jc/XV];
    }
    // async H slice -> hb (NT: single-use stream, don't evict gather set)
    #pragma unroll
    for(int c=0;c<NH4;c++){
      int j = tid + c*512;
      int jc = min(j, hb_lim-1);
      int e = jc/HV4, q = jc - e*HV4;
      gload_lds16<2>(H4 + (size_t)(bstart+e)*32 + p04 + q, ((float4*)hb) + j);
    }
    // async x[src] -> xs (temporal: reused across blocks, keep cached)
    #pragma unroll
    for(int c=0;c<NX4;c++){
      int j = tid + c*512;
      int jc = min(j, xs_lim-1);
      int q = jc - (jc/XV)*XV;
      gload_lds16<0>(x4 + (size_t)sn_r[c]*XV + q, ((float4*)xs) + j);
    }
    __syncthreads();   // drains vmcnt (global_load_lds tracked there)
    // wave-private scatter: wave wid owns node n0+wid
    {
      const int a = ro[wid], b = ro[wid+1];
      if constexpr (PF){
        if(a<b){
          float hv[PP], xv[TI];
          #pragma unroll
          for(int p=0;p<PP;p++) hv[p] = hb[a*PLEN + pw*PP + p];
          #pragma unroll
          for(int u=0;u<TI;u++) xv[u] = xs[a*IC + iw*TI + u];
          for(int e=a; e<b; e++){
            float hn[PP], xn[TI];
            if(e+1<b){
              #pragma unroll
              for(int p=0;p<PP;p++) hn[p] = hb[(e+1)*PLEN + pw*PP + p];
              #pragma unroll
              for(int u=0;u<TI;u++) xn[u] = xs[(e+1)*IC + iw*TI + u];
            }
            #pragma unroll
            for(int p=0;p<PP;p++)
              #pragma unroll
              for(int u=0;u<TI;u++) acc[p][u] += hv[p]*xv[u];
            #pragma unroll
            for(int p=0;p<PP;p++) hv[p]=hn[p];
            #pragma unroll
            for(int u=0;u<TI;u++) xv[u]=xn[u];
          }
        }
      } else {
        for(int e=a; e<b; e++){
          float hv[PP];
          #pragma unroll
          for(int p=0;p<PP;p++) hv[p] = hb[e*PLEN + pw*PP + p];
          float xv[TI];
          #pragma unroll
          for(int u=0;u<TI;u++) xv[u] = xs[e*IC + iw*TI + u];
          #pragma unroll
          for(int p=0;p<PP;p++)
            #pragma unroll
            for(int u=0;u<TI;u++) acc[p][u] += hv[p]*xv[u];
        }
      }
    }
    __syncthreads();
  }

  // dump scaled S (staging area dead); wave wid owns node row wid
  {
    const float dv = 1.f/fmaxf((float)(rs_s[wid+1]-rs_s[wid]), 1.f);
    #pragma unroll
    for(int p=0;p<PP;p++)
      #pragma unroll
      for(int u=0;u<TI;u++)
        S[(wid*PLEN + pw*PP + p)*IC + iw*TI + u] = acc[p][u]*dv;
  }

  // ---- GEMM: slice[n][o] partial over this wave's k-range; coalesced W2 ----
  const int oq  = lane % OQ;
  const int kql = lane / OQ;
  const int o0  = oq*TO;
  const float* W2b = W2 + (size_t)split*K*OC + o0;

  auto LOADW = [&](int j, float (&wv)[4][TO]){
    const int k4 = j*TSPL + wid*KQL + kql;
    #pragma unroll
    for(int r=0;r<4;r++){
      const float* wr = W2b + (size_t)(4*k4+r)*OC;
      if constexpr (TO==4){
        float4 a=*(const float4*)wr;
        wv[r][0]=a.x; wv[r][1]=a.y; wv[r][2]=a.z; wv[r][3]=a.w;
      } else if constexpr (TO==3){
        wv[r][0]=wr[0]; wv[r][1]=wr[1]; wv[r][2]=wr[2];
      } else {
        float2 a=*(const float2*)wr;
        wv[r][0]=a.x; wv[r][1]=a.y;
      }
    }
  };

  float outp[BN][TO];
  #pragma unroll
  for(int n=0;n<BN;n++)
    #pragma unroll
    for(int t=0;t<TO;t++) outp[n][t]=0.f;

  float wvA[4][TO], wvB[4][TO];
  LOADW(0, wvA);          // W2 j=0 in flight across the barrier (independent of S)
  __syncthreads();        // S visible to all waves

  #pragma unroll 1
  for(int j=0;j<J;j+=2){
    LOADW(j+1, wvB);      // prefetch while FMAs on wvA run
    {
      const int k4 = j*TSPL + wid*KQL + kql;
      #pragma unroll
      for(int n=0;n<BN;n++){
        float4 sv = *(const float4*)&S[n*K + 4*k4];
        #pragma unroll
        for(int t=0;t<TO;t++)
          outp[n][t] += sv.x*wvA[0][t] + sv.y*wvA[1][t] + sv.z*wvA[2][t] + sv.w*wvA[3][t];
      }
    }
    if(j+2<J) LOADW(j+2, wvA);   // prefetch while FMAs on wvB run
    {
      const int k4 = (j+1)*TSPL + wid*KQL + kql;
      #pragma unroll
      for(int n=0;n<BN;n++){
        float4 sv = *(const float4*)&S[n*K + 4*k4];
        #pragma unroll
        for(int t=0;t<TO;t++)
          outp[n][t] += sv.x*wvB[0][t] + sv.y*wvB[1][t] + sv.z*wvB[2][t] + sv.w*wvB[3][t];
      }
    }
  }

  // intra-wave reduce over kql lanes (masks OQ..32)
  #pragma unroll
  for(int m=OQ; m<64; m<<=1)
    #pragma unroll
    for(int n=0;n<BN;n++)
      #pragma unroll
      for(int t=0;t<TO;t++) outp[n][t] += __shfl_xor(outp[n][t], m, 64);

  // wave-pair combine: waves 0-3 publish, waves 4-7 add + store slice split*4+(wid-4)
  const int widl = wid & 3;
  if(wid<4 && kql==0){
    #pragma unroll
    for(int n=0;n<BN;n++)
      #pragma unroll
      for(int t=0;t<TO;t++) pad[(widl*BN+n)*OC + o0 + t] = outp[n][t];
  }
  __syncthreads();
  if(wid>=4 && kql==0){
    float* slice = part + (size_t)(split*4+widl)*NN*OC;
    #pragma unroll
    for(int n=0;n<BN;n++){
      #pragma unroll
      for(int t=0;t<TO;t++) outp[n][t] += pad[(widl*BN+n)*OC + o0 + t];
      float* dst = slice + (size_t)(n0+n)*OC + o0;
      if constexpr (TO==4){
        *(float4*)dst = make_float4(outp[n][0],outp[n][1],outp[n][2],outp[n][3]);
      } else if constexpr (TO==3){
        dst[0]=outp[n][0]; dst[1]=outp[n][1]; dst[2]=outp[n][2];
      } else {
        *(float2*)dst = make_float2(outp[n][0],outp[n][1]);
      }
    }
  }
}

// ---------------- epilogue: y = relu(sum_s part[s] + x@root + xbar@b2 + bias) ----------------
template<int IC, int OC, int SL>
__global__ void k_epi(const float* __restrict__ part, const float* __restrict__ x,
                      const float* __restrict__ xbar,
                      const float* __restrict__ root, const float* __restrict__ b2,
                      const float* __restrict__ bias, float* __restrict__ y)
{
  int idx = blockIdx.x*256 + threadIdx.x;
  if(idx >= NN*OC) return;
  int n = idx/OC, o = idx - n*OC;
  float v = bias[o];
  #pragma unroll
  for(int s=0;s<SL;s++) v += part[(size_t)s*NN*OC + idx];
  #pragma unroll
  for(int i=0;i<IC;i++) v += x[(size_t)n*IC+i]*root[i*OC+o];
  #pragma unroll
  for(int i=0;i<IC;i++) v += xbar[(size_t)n*IC+i]*b2[i*OC+o];
  y[idx] = fmaxf(v, 0.f);
}

// ---------------- set2set (2 steps) + final MLP, one wave per graph ----------------
__global__ void k_s2s(const float* __restrict__ xg, const int* __restrict__ batch,
  const float* __restrict__ Wih, const float* __restrict__ Whh,
  const float* __restrict__ bih, const float* __restrict__ bhh,
  const float* __restrict__ l1W, const float* __restrict__ l1b,
  const float* __restrict__ l2W, const float* __restrict__ l2b,
  const float* __restrict__ lfW, const float* __restrict__ lfb,
  float* __restrict__ out)
{
  int g = blockIdx.x, lane = threadIdx.x;
  __shared__ float hs[16], cs[16], qs[32], gs[64], rs[16];
  int r0 = lowerb(batch, NN, g);
  int r1 = lowerb(batch, NN, g+1);
  if(lane<16){ hs[lane]=0.f; cs[lane]=0.f; }
  if(lane<32) qs[lane]=0.f;
  __syncthreads();
  for(int step=0; step<2; step++){
    float gate = bih[lane] + bhh[lane];
    for(int k=0;k<32;k++) gate += qs[k]*Wih[lane*32+k];
    for(int k=0;k<16;k++) gate += hs[k]*Whh[lane*16+k];
    gs[lane] = gate;
    __syncthreads();
    if(lane<16){
      float ig = 1.f/(1.f+expf(-gs[lane]));
      float fg = 1.f/(1.f+expf(-gs[lane+16]));
      float gg = tanhf(gs[lane+32]);
      float og = 1.f/(1.f+expf(-gs[lane+48]));
      float cn = fg*cs[lane] + ig*gg;
      cs[lane] = cn;
      hs[lane] = og*tanhf(cn);
    }
    __syncthreads();
    float m = -1e30f;
    for(int n=r0+lane; n<r1; n+=64){
      float e=0.f;
      for(int k=0;k<16;k++) e += xg[n*16+k]*hs[k];
      m = fmaxf(m, e);
    }
    for(int d=1; d<64; d<<=1) m = fmaxf(m, __shfl_xor(m, d));
    float ssum = 0.f;
    float racc[16];
    #pragma unroll
    for(int k=0;k<16;k++) racc[k]=0.f;
    for(int n=r0+lane; n<r1; n+=64){
      float e=0.f, xv[16];
      #pragma unroll
      for(int k=0;k<16;k++){ xv[k]=xg[n*16+k]; e += xv[k]*hs[k]; }
      float a = expf(e - m);
      ssum += a;
      #pragma unroll
      for(int k=0;k<16;k++) racc[k] += a*xv[k];
    }
    for(int d=1; d<64; d<<=1) ssum += __shfl_xor(ssum, d);
    #pragma unroll
    for(int k=0;k<16;k++)
      for(int d=1; d<64; d<<=1) racc[k] += __shfl_xor(racc[k], d);
    ssum = fmaxf(ssum, 1e-16f);
    if(lane==0){
      #pragma unroll
      for(int k=0;k<16;k++) rs[k] = racc[k]/ssum;
    }
    __syncthreads();
    if(lane<16){ qs[lane]=hs[lane]; qs[16+lane]=rs[lane]; }
    __syncthreads();
  }
  if(lane<16){
    float v = l1b[lane];
    for(int k=0;k<32;k++) v += qs[k]*l1W[k*16+lane];
    gs[lane] = fmaxf(v,0.f);
  }
  __syncthreads();
  if(lane<8){
    float v = l2b[lane];
    for(int k=0;k<16;k++) v += gs[k]*l2W[k*8+lane];
    gs[32+lane] = fmaxf(v,0.f);
  }
  __syncthreads();
  if(lane==0){
    float v = lfb[0];
    for(int k=0;k<8;k++) v += gs[32+k]*lfW[k];
    out[g] = v;
  }
}

extern "C" void kernel_launch(void* const* d_in, const int* in_sizes, int n_in,
                              void* d_out, int out_size, void* d_ws, size_t ws_size,
                              hipStream_t stream) {
  const float* x0   = (const float*)d_in[0];
  const int*   ei   = (const int*)d_in[1];
  const float* ea   = (const float*)d_in[2];
  const int*   batch= (const int*)d_in[3];
  const float* c1W1 = (const float*)d_in[4];  const float* c1b1 = (const float*)d_in[5];
  const float* c1W2 = (const float*)d_in[6];  const float* c1b2 = (const float*)d_in[7];
  const float* c1rt = (const float*)d_in[8];  const float* c1bs = (const float*)d_in[9];
  const float* c2W1 = (const float*)d_in[10]; const float* c2b1 = (const float*)d_in[11];
  const float* c2W2 = (const float*)d_in[12]; const float* c2b2 = (const float*)d_in[13];
  const float* c2rt = (const float*)d_in[14]; const float* c2bs = (const float*)d_in[15];
  const float* c3W1 = (const float*)d_in[16]; const float* c3b1 = (const float*)d_in[17];
  const float* c3W2 = (const float*)d_in[18]; const float* c3b2 = (const float*)d_in[19];
  const float* c3rt = (const float*)d_in[20]; const float* c3bs = (const float*)d_in[21];
  const float* Wih  = (const float*)d_in[22]; const float* Whh  = (const float*)d_in[23];
  const float* bih  = (const float*)d_in[24]; const float* bhh  = (const float*)d_in[25];
  const float* l1W  = (const float*)d_in[26]; const float* l1b  = (const float*)d_in[27];
  const float* l2W  = (const float*)d_in[28]; const float* l2b  = (const float*)d_in[29];
  const float* lfW  = (const float*)d_in[30]; const float* lfb  = (const float*)d_in[31];
  float* out = (float*)d_out;

  const int* src = ei;
  const int* tgt = ei + NE;

  // workspace carve (~190 MB)
  char* w = (char*)d_ws;
  auto carve = [&](size_t bytes)->void*{ void* p = (void*)w; w += (bytes + 255) & ~(size_t)255; return p; };
  int*   row_start = (int*)carve((NN+1)*sizeof(int));
  int*   cur       = (int*)carve(NN*sizeof(int));
  int*   es_src    = (int*)carve(NE*sizeof(int));
  float* es_ea     = (float*)carve((size_t)NE*16*sizeof(float));
  float* Hbuf      = (float*)carve((size_t)NE*128*sizeof(float));
  float* xbar      = (float*)carve((size_t)NN*48*sizeof(float));
  float* y1   = (float*)carve((size_t)NN*48*sizeof(float));
  float* y2   = (float*)carve((size_t)NN*32*sizeof(float));
  float* y3   = (float*)carve((size_t)NN*16*sizeof(float));
  float* part = (float*)carve((size_t)16*NN*48*sizeof(float)); // up to 16 slices

  // ---- CSR by tgt (+ fused ea gather)
  hipMemsetAsync(cur, 0, NN*sizeof(int), stream);
  k_count<<<(NE+255)/256, 256, 0, stream>>>(tgt, cur);
  k_scan<<<1, 1024, 0, stream>>>(cur, row_start);
  hipMemsetAsync(cur, 0, NN*sizeof(int), stream);
  k_place<<<(NE+255)/256, 256, 0, stream>>>(src, tgt, ea, row_start, cur, es_src, es_ea);

  // ---- layer 1: IC=16 OC=48 | PLEN=64 KS=2 BN=8 PP=4 TI=4 | OQ=16 TO=3 | PF on, EB=96 (8 slices)
  k_hmlp<<<NE/8, 256, 0, stream>>>(es_ea, c1W1, c1b1, Hbuf);
  k_xbar<16><<<NN/4, 256, 0, stream>>>(x0, es_src, row_start, xbar);
  k_layer<16,48,64,2,8,4,4,16,3,true,96><<<(NN/8)*2, 512, 0, stream>>>(x0, Hbuf, es_src, row_start, c1W2, part);
  k_epi<16,48,8><<<(NN*48+255)/256, 256, 0, stream>>>(part, x0, xbar, c1rt, c1b2, c1bs, y1);

  // ---- layer 2: IC=48 OC=32 | PLEN=32 KS=4 BN=8 PP=4 TI=6 | OQ=8 TO=4 | PF on, EB=128 (16 slices)
  k_hmlp<<<NE/8, 256, 0, stream>>>(es_ea, c2W1, c2b1, Hbuf);
  k_xbar<48><<<NN/4, 256, 0, stream>>>(y1, es_src, row_start, xbar);
  k_layer<48,32,32,4,8,4,6,8,4,true,128><<<(NN/8)*4, 512, 0, stream>>>(y1, Hbuf, es_src, row_start, c2W2, part);
  k_epi<48,32,16><<<(NN*32+255)/256, 256, 0, stream>>>(part, y1, xbar, c2rt, c2b2, c2bs, y2);

  // ---- layer 3: IC=32 OC=16 | PLEN=32 KS=4 BN=8 PP=4 TI=4 | OQ=4 TO=4 | PF on, EB=128 (16 slices)
  k_hmlp<<<NE/8, 256, 0, stream>>>(es_ea, c3W1, c3b1, Hbuf);
  k_xbar<32><<<NN/4, 256, 0, stream>>>(y2, es_src, row_start, xbar);
  k_layer<32,16,32,4,8,4,4,4,4,true,128><<<(NN/8)*4, 512, 0, stream>>>(y2, Hbuf, es_src, row_start, c3W2, part);
  k_epi<32,16,16><<<(NN*16+255)/256, 256, 0, stream>>>(part, y2, xbar, c3rt, c3b2, c3bs, y3);

  // ---- set2set + MLP head
  k_s2s<<<NG, 64, 0, stream>>>(y3, batch, Wih, Whh, bih, bhh, l1W, l1b, l2W, l2b, lfW, lfb, out);
}

// Round 7
// 871.158 us; speedup vs baseline: 2.2295x; 1.2414x over previous
//
#include <hip/hip_runtime.h>

#define NN 20000
#define NE 200000
#define NG 512

__device__ __forceinline__ int lowerb(const int* a, int n, int v){
  int lo=0, hi=n;
  while(lo<hi){ int m=(lo+hi)>>1; if(a[m]<v) lo=m+1; else hi=m; }
  return lo;
}

// async global->LDS copy, 16B per lane. LDS dest must be linear in lane order
// (wave-uniform base + lane*16). AUX=2 sets NT (evict-first): H stream is single-use.
template<int AUX>
__device__ __forceinline__ void gload_lds16(const float4* g, float4* l){
  __builtin_amdgcn_global_load_lds(
    (const __attribute__((address_space(1))) void*)(g),
    (__attribute__((address_space(3))) void*)(l), 16, 0, AUX);
}

// ---------------- counting sort by tgt -> CSR ----------------
__global__ void k_count(const int* __restrict__ tgt, int* __restrict__ cnt){
  int e = blockIdx.x*blockDim.x + threadIdx.x;
  if(e<NE) atomicAdd(&cnt[tgt[e]], 1);
}

__global__ void k_scan(const int* __restrict__ cnt, int* __restrict__ row_start){
  __shared__ int part[1024];
  int t = threadIdx.x;
  const int CH = (NN + 1023)/1024; // 20
  int i0 = t*CH;
  int s = 0;
  for(int j=0;j<CH;j++){ int i=i0+j; if(i<NN) s += cnt[i]; }
  part[t] = s; __syncthreads();
  for(int d=1; d<1024; d<<=1){
    int v = (t>=d) ? part[t-d] : 0;
    __syncthreads();
    part[t] += v;
    __syncthreads();
  }
  int run = (t==0) ? 0 : part[t-1];
  for(int j=0;j<CH;j++){ int i=i0+j; if(i<NN){ row_start[i]=run; run += cnt[i]; } }
  if(t==0) row_start[NN] = part[1023];
}

// place edges in CSR order AND gather edge_attr to CSR order (fused)
__global__ void k_place(const int* __restrict__ src, const int* __restrict__ tgt,
                        const float* __restrict__ ea,
                        const int* __restrict__ row_start, int* __restrict__ cur,
                        int* __restrict__ es_src, float* __restrict__ es_ea){
  int e = blockIdx.x*blockDim.x + threadIdx.x;
  if(e>=NE) return;
  int n = tgt[e];
  int pos = row_start[n] + atomicAdd(&cur[n],1);
  es_src[pos] = src[e];
  const float4* s = (const float4*)ea + (size_t)e*4;
  float4* d = (float4*)es_ea + (size_t)pos*4;
  d[0]=s[0]; d[1]=s[1]; d[2]=s[2]; d[3]=s[3];
}

// ---------------- H = relu(es_ea @ W1 + b1), CSR-ordered, E x 128 ----------------
__launch_bounds__(256, 4)
__global__ void k_hmlp(const float* __restrict__ es_ea, const float* __restrict__ W1,
                       const float* __restrict__ b1, float* __restrict__ H){
  const int pc = threadIdx.x & 31, er = threadIdx.x >> 5;
  const size_t e = (size_t)blockIdx.x*8 + er;
  float4 w1v[16];
  #pragma unroll
  for(int i=0;i<16;i++) w1v[i] = *(const float4*)&W1[i*128 + pc*4];
  float4 hv = *(const float4*)&b1[pc*4];
  float eav[16];
  const float4* eap = (const float4*)(es_ea + e*16);
  #pragma unroll
  for(int q=0;q<4;q++){
    float4 v = eap[q];
    eav[q*4+0]=v.x; eav[q*4+1]=v.y; eav[q*4+2]=v.z; eav[q*4+3]=v.w;
  }
  #pragma unroll
  for(int i=0;i<16;i++){
    hv.x += eav[i]*w1v[i].x;
    hv.y += eav[i]*w1v[i].y;
    hv.z += eav[i]*w1v[i].z;
    hv.w += eav[i]*w1v[i].w;
  }
  hv.x = fmaxf(hv.x,0.f); hv.y = fmaxf(hv.y,0.f);
  hv.z = fmaxf(hv.z,0.f); hv.w = fmaxf(hv.w,0.f);
  *(float4*)&H[e*128 + pc*4] = hv;
}

// ---------------- xbar[n,i] = mean over in-edges of x[src,i] ----------------
template<int IC>
__global__ void k_xbar(const float* __restrict__ x, const int* __restrict__ es_src,
                       const int* __restrict__ row_start, float* __restrict__ xbar){
  constexpr int TI = IC/16;
  const int wid = threadIdx.x>>6, lane = threadIdx.x&63;
  const int n = blockIdx.x*4 + wid;
  const int eg = lane>>4, ig = lane&15;
  const int a = row_start[n], b = row_start[n+1];
  float s[TI];
  #pragma unroll
  for(int u=0;u<TI;u++) s[u]=0.f;
  for(int e=a+eg; e<b; e+=4){
    int sn = es_src[e];
    #pragma unroll
    for(int u=0;u<TI;u++) s[u] += x[(size_t)sn*IC + ig*TI + u];
  }
  #pragma unroll
  for(int u=0;u<TI;u++){
    s[u] += __shfl_xor(s[u], 16, 64);
    s[u] += __shfl_xor(s[u], 32, 64);
  }
  if(eg==0){
    float dinv = 1.f/fmaxf((float)(b-a), 1.f);
    #pragma unroll
    for(int u=0;u<TI;u++) xbar[(size_t)n*IC + ig*TI + u] = s[u]*dinv;
  }
}

// ---------------- fused NNConv layer: wave-private scatter + coalesced k-split GEMM ----------------
// Round 7: BN=4 at 256 threads, tested CLEANLY this time (round 4 bundled it with the
// min-waves=6 allocator spill). Measured constraints driving this:
//  - LDS/block sets blocks/CU: round-3 48.5KB -> 3 blocks x 4 waves = 12 waves (31%).
//  - VGPR quantization (steps 64/128/256): >64 VGPR caps 4 waves/SIMD. Round 6's
//    8-wave blocks hit this (16 waves as 2 big blocks -> barrier convoy, 23% occ).
// BN=4 shrinks LDS to ~17-25KB (6+ blocks/CU) AND halves acc (48->24 floats) +
// outp (32->16), so VGPR should land <=64 ORGANICALLY -> 8 waves/SIMD -> 24 waves/CU.
// NEVER force via __launch_bounds__ min-waves: =6 twice squeezed VGPR to 40 + GB-scale
// scratch spill (rounds 4,5). Keep (256,3) exactly as the proven round-3 build.
// Cost: W2 L2-reads x2 for L1/L2 (~+2GB L2 @ 34.5TB/s ~ 60us aggregate) -- acceptable.
// L3 keeps its round-3-proven config (already BN=4).
// Staging: global_load_lds w=16 (NT for single-use H stream); drained at barrier.
// GEMM: W2-only ping-pong prefetch (round-2 win); S reads in-iteration (round-1
// lesson: double-buffering both spilled). No-spill check: FETCH~100-140MB, WRITE 40MB.
template<int IC, int OC, int PLEN, int KS, int BN, int PP, int TI, int OQ, int TO, bool PF, int EB>
__launch_bounds__(256, 3)
__global__ void k_layer(const float* __restrict__ x_in, const float* __restrict__ H,
                        const int* __restrict__ es_src, const int* __restrict__ row_start,
                        const float* __restrict__ W2, float* __restrict__ part)
{
  constexpr int K    = PLEN*IC;
  constexpr int HV4  = PLEN/4;
  constexpr int XV   = IC/4;
  constexpr int NIW  = IC/TI;
  constexpr int NPW  = PLEN/PP;
  constexpr int G    = BN/4;
  constexpr int KQL  = 64/OQ;
  constexpr int TSPL = 4*KQL;
  constexpr int J    = (K/4)/TSPL;
  constexpr int NH4  = (EB*HV4 + 255)/256;   // hb staging chunks
  constexpr int NX4  = (EB*XV  + 255)/256;   // xs staging chunks
  static_assert(NPW*NIW==64, "wave tile covers 64 lanes");
  static_assert(G*PP*TI <= 48, "spill-safe accumulator");
  static_assert(EB*(PLEN+IC) <= BN*K, "staging alias fits in S");
  static_assert((EB*HV4)%256==0, "hb tail must not round into xs region");
  static_assert(EB*PLEN/4 + NX4*256 <= BN*K/4, "xs tail rounding stays inside S");
  static_assert(OQ*TO==OC && (K/4)%TSPL==0, "gemm tiling");
  static_assert(J%2==0, "ping-pong needs even J");

  __shared__ __align__(16) float S[BN*K];
  __shared__ int rs_s[BN+1], ro[BN+1];

  float* hb = S;                 // EB*PLEN staged H slice
  float* xs = S + EB*PLEN;       // EB*IC staged x[src]

  const int tid = threadIdx.x;
  const int wid = tid>>6, lane = tid&63;
  const int split = blockIdx.x % KS;
  const int nb = blockIdx.x / KS;
  const int n0 = nb*BN;
  const int p04 = split*HV4;

  if(tid<=BN) rs_s[tid] = row_start[n0+tid];
  __syncthreads();
  const int estart = rs_s[0], eend = rs_s[BN];

  const int pw = lane / NIW;
  const int iw = lane - pw*NIW;

  float acc[G][PP][TI];
  #pragma unroll
  for(int g=0;g<G;g++)
    #pragma unroll
    for(int p=0;p<PP;p++)
      #pragma unroll
      for(int u=0;u<TI;u++) acc[g][p][u]=0.f;

  const float4* H4 = (const float4*)H;
  const float4* x4 = (const float4*)x_in;

  for(int bstart=estart; bstart<eend; bstart+=EB){
    const int ebc = min(EB, eend-bstart);
    if(tid<=BN){ int v = rs_s[tid]-bstart; ro[tid] = min(max(v,0), ebc); }
    const int hb_lim = ebc*HV4, xs_lim = ebc*XV;
    // pre-load gather indices (independent loads, issued together)
    int sn_r[NX4];
    #pragma unroll
    for(int c=0;c<NX4;c++){
      int jc = min(tid + c*256, xs_lim-1);
      sn_r[c] = es_src[bstart + jc/XV];
    }
    // async H slice -> hb (NT: single-use stream)
    #pragma unroll
    for(int c=0;c<NH4;c++){
      int j = tid + c*256;
      int jc = min(j, hb_lim-1);
      int e = jc/HV4, q = jc - e*HV4;
      gload_lds16<2>(H4 + (size_t)(bstart+e)*32 + p04 + q, ((float4*)hb) + j);
    }
    // async x[src] -> xs (temporal: reused across blocks)
    #pragma unroll
    for(int c=0;c<NX4;c++){
      int j = tid + c*256;
      int jc = min(j, xs_lim-1);
      int q = jc - (jc/XV)*XV;
      gload_lds16<0>(x4 + (size_t)sn_r[c]*XV + q, ((float4*)xs) + j);
    }
    __syncthreads();   // drains vmcnt (global_load_lds tracked there)
    // wave-private scatter (only the owning wave touches its nodes' edges)
    if constexpr (PF){
      #pragma unroll
      for(int g=0; g<G; g++){
        const int nl = wid*G + g;
        const int a = ro[nl], b = ro[nl+1];
        if(a>=b) continue;
        float hv[PP], xv[TI];
        #pragma unroll
        for(int p=0;p<PP;p++) hv[p] = hb[a*PLEN + pw*PP + p];
        #pragma unroll
        for(int u=0;u<TI;u++) xv[u] = xs[a*IC + iw*TI + u];
        for(int e=a; e<b; e++){
          float hn[PP], xn[TI];
          if(e+1<b){
            #pragma unroll
            for(int p=0;p<PP;p++) hn[p] = hb[(e+1)*PLEN + pw*PP + p];
            #pragma unroll
            for(int u=0;u<TI;u++) xn[u] = xs[(e+1)*IC + iw*TI + u];
          }
          #pragma unroll
          for(int p=0;p<PP;p++)
            #pragma unroll
            for(int u=0;u<TI;u++) acc[g][p][u] += hv[p]*xv[u];
          #pragma unroll
          for(int p=0;p<PP;p++) hv[p]=hn[p];
          #pragma unroll
          for(int u=0;u<TI;u++) xv[u]=xn[u];
        }
      }
    } else {
      #pragma unroll
      for(int g=0; g<G; g++){
        const int nl = wid*G + g;
        const int a = ro[nl], b = ro[nl+1];
        for(int e=a; e<b; e++){
          float hv[PP];
          #pragma unroll
          for(int p=0;p<PP;p++) hv[p] = hb[e*PLEN + pw*PP + p];
          float xv[TI];
          #pragma unroll
          for(int u=0;u<TI;u++) xv[u] = xs[e*IC + iw*TI + u];
          #pragma unroll
          for(int p=0;p<PP;p++)
            #pragma unroll
            for(int u=0;u<TI;u++) acc[g][p][u] += hv[p]*xv[u];
        }
      }
    }
    __syncthreads();
  }

  // dump scaled S (staging area dead)
  #pragma unroll
  for(int g=0; g<G; g++){
    const int nl = wid*G + g;
    const float dv = 1.f/fmaxf((float)(rs_s[nl+1]-rs_s[nl]), 1.f);
    #pragma unroll
    for(int p=0;p<PP;p++)
      #pragma unroll
      for(int u=0;u<TI;u++)
        S[(nl*PLEN + pw*PP + p)*IC + iw*TI + u] = acc[g][p][u]*dv;
  }

  // ---- GEMM: slice[n][o] partial over this wave's k-range; coalesced W2 ----
  const int oq  = lane % OQ;
  const int kql = lane / OQ;
  const int o0  = oq*TO;
  const float* W2b = W2 + (size_t)split*K*OC + o0;

  auto LOADW = [&](int j, float (&wv)[4][TO]){
    const int k4 = j*TSPL + wid*KQL + kql;
    #pragma unroll
    for(int r=0;r<4;r++){
      const float* wr = W2b + (size_t)(4*k4+r)*OC;
      if constexpr (TO==4){
        float4 a=*(const float4*)wr;
        wv[r][0]=a.x; wv[r][1]=a.y; wv[r][2]=a.z; wv[r][3]=a.w;
      } else if constexpr (TO==3){
        wv[r][0]=wr[0]; wv[r][1]=wr[1]; wv[r][2]=wr[2];
      } else {
        float2 a=*(const float2*)wr;
        wv[r][0]=a.x; wv[r][1]=a.y;
      }
    }
  };

  float outp[BN][TO];
  #pragma unroll
  for(int n=0;n<BN;n++)
    #pragma unroll
    for(int t=0;t<TO;t++) outp[n][t]=0.f;

  float wvA[4][TO], wvB[4][TO];
  LOADW(0, wvA);          // W2 j=0 in flight across the barrier (independent of S)
  __syncthreads();        // S visible to all waves

  #pragma unroll 1
  for(int j=0;j<J;j+=2){
    LOADW(j+1, wvB);      // prefetch while FMAs on wvA run
    {
      const int k4 = j*TSPL + wid*KQL + kql;
      #pragma unroll
      for(int n=0;n<BN;n++){
        float4 sv = *(const float4*)&S[n*K + 4*k4];
        #pragma unroll
        for(int t=0;t<TO;t++)
          outp[n][t] += sv.x*wvA[0][t] + sv.y*wvA[1][t] + sv.z*wvA[2][t] + sv.w*wvA[3][t];
      }
    }
    if(j+2<J) LOADW(j+2, wvA);   // prefetch while FMAs on wvB run
    {
      const int k4 = (j+1)*TSPL + wid*KQL + kql;
      #pragma unroll
      for(int n=0;n<BN;n++){
        float4 sv = *(const float4*)&S[n*K + 4*k4];
        #pragma unroll
        for(int t=0;t<TO;t++)
          outp[n][t] += sv.x*wvB[0][t] + sv.y*wvB[1][t] + sv.z*wvB[2][t] + sv.w*wvB[3][t];
      }
    }
  }

  // intra-wave reduce over kql lanes (masks OQ..32)
  #pragma unroll
  for(int m=OQ; m<64; m<<=1)
    #pragma unroll
    for(int n=0;n<BN;n++)
      #pragma unroll
      for(int t=0;t<TO;t++) outp[n][t] += __shfl_xor(outp[n][t], m, 64);

  if(kql==0){
    float* slice = part + (size_t)(split*4+wid)*NN*OC;
    #pragma unroll
    for(int n=0;n<BN;n++){
      float* dst = slice + (size_t)(n0+n)*OC + o0;
      if constexpr (TO==4){
        *(float4*)dst = make_float4(outp[n][0],outp[n][1],outp[n][2],outp[n][3]);
      } else if constexpr (TO==3){
        dst[0]=outp[n][0]; dst[1]=outp[n][1]; dst[2]=outp[n][2];
      } else {
        *(float2*)dst = make_float2(outp[n][0],outp[n][1]);
      }
    }
  }
}

// ---------------- epilogue: y = relu(sum_s part[s] + x@root + xbar@b2 + bias) ----------------
template<int IC, int OC, int SL>
__global__ void k_epi(const float* __restrict__ part, const float* __restrict__ x,
                      const float* __restrict__ xbar,
                      const float* __restrict__ root, const float* __restrict__ b2,
                      const float* __restrict__ bias, float* __restrict__ y)
{
  int idx = blockIdx.x*256 + threadIdx.x;
  if(idx >= NN*OC) return;
  int n = idx/OC, o = idx - n*OC;
  float v = bias[o];
  #pragma unroll
  for(int s=0;s<SL;s++) v += part[(size_t)s*NN*OC + idx];
  #pragma unroll
  for(int i=0;i<IC;i++) v += x[(size_t)n*IC+i]*root[i*OC+o];
  #pragma unroll
  for(int i=0;i<IC;i++) v += xbar[(size_t)n*IC+i]*b2[i*OC+o];
  y[idx] = fmaxf(v, 0.f);
}

// ---------------- set2set (2 steps) + final MLP, one wave per graph ----------------
__global__ void k_s2s(const float* __restrict__ xg, const int* __restrict__ batch,
  const float* __restrict__ Wih, const float* __restrict__ Whh,
  const float* __restrict__ bih, const float* __restrict__ bhh,
  const float* __restrict__ l1W, const float* __restrict__ l1b,
  const float* __restrict__ l2W, const float* __restrict__ l2b,
  const float* __restrict__ lfW, const float* __restrict__ lfb,
  float* __restrict__ out)
{
  int g = blockIdx.x, lane = threadIdx.x;
  __shared__ float hs[16], cs[16], qs[32], gs[64], rs[16];
  int r0 = lowerb(batch, NN, g);
  int r1 = lowerb(batch, NN, g+1);
  if(lane<16){ hs[lane]=0.f; cs[lane]=0.f; }
  if(lane<32) qs[lane]=0.f;
  __syncthreads();
  for(int step=0; step<2; step++){
    float gate = bih[lane] + bhh[lane];
    for(int k=0;k<32;k++) gate += qs[k]*Wih[lane*32+k];
    for(int k=0;k<16;k++) gate += hs[k]*Whh[lane*16+k];
    gs[lane] = gate;
    __syncthreads();
    if(lane<16){
      float ig = 1.f/(1.f+expf(-gs[lane]));
      float fg = 1.f/(1.f+expf(-gs[lane+16]));
      float gg = tanhf(gs[lane+32]);
      float og = 1.f/(1.f+expf(-gs[lane+48]));
      float cn = fg*cs[lane] + ig*gg;
      cs[lane] = cn;
      hs[lane] = og*tanhf(cn);
    }
    __syncthreads();
    float m = -1e30f;
    for(int n=r0+lane; n<r1; n+=64){
      float e=0.f;
      for(int k=0;k<16;k++) e += xg[n*16+k]*hs[k];
      m = fmaxf(m, e);
    }
    for(int d=1; d<64; d<<=1) m = fmaxf(m, __shfl_xor(m, d));
    float ssum = 0.f;
    float racc[16];
    #pragma unroll
    for(int k=0;k<16;k++) racc[k]=0.f;
    for(int n=r0+lane; n<r1; n+=64){
      float e=0.f, xv[16];
      #pragma unroll
      for(int k=0;k<16;k++){ xv[k]=xg[n*16+k]; e += xv[k]*hs[k]; }
      float a = expf(e - m);
      ssum += a;
      #pragma unroll
      for(int k=0;k<16;k++) racc[k] += a*xv[k];
    }
    for(int d=1; d<64; d<<=1) ssum += __shfl_xor(ssum, d);
    #pragma unroll
    for(int k=0;k<16;k++)
      for(int d=1; d<64; d<<=1) racc[k] += __shfl_xor(racc[k], d);
    ssum = fmaxf(ssum, 1e-16f);
    if(lane==0){
      #pragma unroll
      for(int k=0;k<16;k++) rs[k] = racc[k]/ssum;
    }
    __syncthreads();
    if(lane<16){ qs[lane]=hs[lane]; qs[16+lane]=rs[lane]; }
    __syncthreads();
  }
  if(lane<16){
    float v = l1b[lane];
    for(int k=0;k<32;k++) v += qs[k]*l1W[k*16+lane];
    gs[lane] = fmaxf(v,0.f);
  }
  __syncthreads();
  if(lane<8){
    float v = l2b[lane];
    for(int k=0;k<16;k++) v += gs[k]*l2W[k*8+lane];
    gs[32+lane] = fmaxf(v,0.f);
  }
  __syncthreads();
  if(lane==0){
    float v = lfb[0];
    for(int k=0;k<8;k++) v += gs[32+k]*lfW[k];
    out[g] = v;
  }
}

extern "C" void kernel_launch(void* const* d_in, const int* in_sizes, int n_in,
                              void* d_out, int out_size, void* d_ws, size_t ws_size,
                              hipStream_t stream) {
  const float* x0   = (const float*)d_in[0];
  const int*   ei   = (const int*)d_in[1];
  const float* ea   = (const float*)d_in[2];
  const int*   batch= (const int*)d_in[3];
  const float* c1W1 = (const float*)d_in[4];  const float* c1b1 = (const float*)d_in[5];
  const float* c1W2 = (const float*)d_in[6];  const float* c1b2 = (const float*)d_in[7];
  const float* c1rt = (const float*)d_in[8];  const float* c1bs = (const float*)d_in[9];
  const float* c2W1 = (const float*)d_in[10]; const float* c2b1 = (const float*)d_in[11];
  const float* c2W2 = (const float*)d_in[12]; const float* c2b2 = (const float*)d_in[13];
  const float* c2rt = (const float*)d_in[14]; const float* c2bs = (const float*)d_in[15];
  const float* c3W1 = (const float*)d_in[16]; const float* c3b1 = (const float*)d_in[17];
  const float* c3W2 = (const float*)d_in[18]; const float* c3b2 = (const float*)d_in[19];
  const float* c3rt = (const float*)d_in[20]; const float* c3bs = (const float*)d_in[21];
  const float* Wih  = (const float*)d_in[22]; const float* Whh  = (const float*)d_in[23];
  const float* bih  = (const float*)d_in[24]; const float* bhh  = (const float*)d_in[25];
  const float* l1W  = (const float*)d_in[26]; const float* l1b  = (const float*)d_in[27];
  const float* l2W  = (const float*)d_in[28]; const float* l2b  = (const float*)d_in[29];
  const float* lfW  = (const float*)d_in[30]; const float* lfb  = (const float*)d_in[31];
  float* out = (float*)d_out;

  const int* src = ei;
  const int* tgt = ei + NE;

  // workspace carve (~190 MB)
  char* w = (char*)d_ws;
  auto carve = [&](size_t bytes)->void*{ void* p = (void*)w; w += (bytes + 255) & ~(size_t)255; return p; };
  int*   row_start = (int*)carve((NN+1)*sizeof(int));
  int*   cur       = (int*)carve(NN*sizeof(int));
  int*   es_src    = (int*)carve(NE*sizeof(int));
  float* es_ea     = (float*)carve((size_t)NE*16*sizeof(float));
  float* Hbuf      = (float*)carve((size_t)NE*128*sizeof(float));
  float* xbar      = (float*)carve((size_t)NN*48*sizeof(float));
  float* y1   = (float*)carve((size_t)NN*48*sizeof(float));
  float* y2   = (float*)carve((size_t)NN*32*sizeof(float));
  float* y3   = (float*)carve((size_t)NN*16*sizeof(float));
  float* part = (float*)carve((size_t)16*NN*48*sizeof(float)); // up to 16 slices

  // ---- CSR by tgt (+ fused ea gather)
  hipMemsetAsync(cur, 0, NN*sizeof(int), stream);
  k_count<<<(NE+255)/256, 256, 0, stream>>>(tgt, cur);
  k_scan<<<1, 1024, 0, stream>>>(cur, row_start);
  hipMemsetAsync(cur, 0, NN*sizeof(int), stream);
  k_place<<<(NE+255)/256, 256, 0, stream>>>(src, tgt, ea, row_start, cur, es_src, es_ea);

  // ---- layer 1: IC=16 OC=48 | PLEN=64 KS=2 BN=4 G=1 PP=4 TI=4 | OQ=16 TO=3 | PF on, EB=48 (8 slices)
  k_hmlp<<<NE/8, 256, 0, stream>>>(es_ea, c1W1, c1b1, Hbuf);
  k_xbar<16><<<NN/4, 256, 0, stream>>>(x0, es_src, row_start, xbar);
  k_layer<16,48,64,2,4,4,4,16,3,true,48><<<(NN/4)*2, 256, 0, stream>>>(x0, Hbuf, es_src, row_start, c1W2, part);
  k_epi<16,48,8><<<(NN*48+255)/256, 256, 0, stream>>>(part, x0, xbar, c1rt, c1b2, c1bs, y1);

  // ---- layer 2: IC=48 OC=32 | PLEN=32 KS=4 BN=4 G=1 PP=4 TI=6 | OQ=8 TO=4 | PF on, EB=64 (16 slices)
  k_hmlp<<<NE/8, 256, 0, stream>>>(es_ea, c2W1, c2b1, Hbuf);
  k_xbar<48><<<NN/4, 256, 0, stream>>>(y1, es_src, row_start, xbar);
  k_layer<48,32,32,4,4,4,6,8,4,true,64><<<(NN/4)*4, 256, 0, stream>>>(y1, Hbuf, es_src, row_start, c2W2, part);
  k_epi<48,32,16><<<(NN*32+255)/256, 256, 0, stream>>>(part, y1, xbar, c2rt, c2b2, c2bs, y2);

  // ---- layer 3: IC=32 OC=16 | PLEN=64 KS=2 BN=4 G=1 PP=4 TI=8 | OQ=4 TO=4 | PF on, EB=64 (8 slices) -- round-3-proven
  k_hmlp<<<NE/8, 256, 0, stream>>>(es_ea, c3W1, c3b1, Hbuf);
  k_xbar<32><<<NN/4, 256, 0, stream>>>(y2, es_src, row_start, xbar);
  k_layer<32,16,64,2,4,4,8,4,4,true,64><<<(NN/4)*2, 256, 0, stream>>>(y2, Hbuf, es_src, row_start, c3W2, part);
  k_epi<32,16,8><<<(NN*16+255)/256, 256, 0, stream>>>(part, y2, xbar, c3rt, c3b2, c3bs, y3);

  // ---- set2set + MLP head
  k_s2s<<<NG, 64, 0, stream>>>(y3, batch, Wih, Whh, bih, bhh, l1W, l1b, l2W, l2b, lfW, lfb, out);
}

// Round 8
// 840.367 us; speedup vs baseline: 2.3112x; 1.0366x over previous
//
#include <hip/hip_runtime.h>

#define NN 20000
#define NE 200000
#define NG 512

__device__ __forceinline__ int lowerb(const int* a, int n, int v){
  int lo=0, hi=n;
  while(lo<hi){ int m=(lo+hi)>>1; if(a[m]<v) lo=m+1; else hi=m; }
  return lo;
}

// async global->LDS copy, 16B per lane. LDS dest must be linear in lane order
// (wave-uniform base + lane*16). AUX=2 sets NT (evict-first): H stream is single-use.
template<int AUX>
__device__ __forceinline__ void gload_lds16(const float4* g, float4* l){
  __builtin_amdgcn_global_load_lds(
    (const __attribute__((address_space(1))) void*)(g),
    (__attribute__((address_space(3))) void*)(l), 16, 0, AUX);
}

// ---------------- counting sort by tgt -> CSR ----------------
__global__ void k_count(const int* __restrict__ tgt, int* __restrict__ cnt){
  int e = blockIdx.x*blockDim.x + threadIdx.x;
  if(e<NE) atomicAdd(&cnt[tgt[e]], 1);
}

__global__ void k_scan(const int* __restrict__ cnt, int* __restrict__ row_start){
  __shared__ int part[1024];
  int t = threadIdx.x;
  const int CH = (NN + 1023)/1024; // 20
  int i0 = t*CH;
  int s = 0;
  for(int j=0;j<CH;j++){ int i=i0+j; if(i<NN) s += cnt[i]; }
  part[t] = s; __syncthreads();
  for(int d=1; d<1024; d<<=1){
    int v = (t>=d) ? part[t-d] : 0;
    __syncthreads();
    part[t] += v;
    __syncthreads();
  }
  int run = (t==0) ? 0 : part[t-1];
  for(int j=0;j<CH;j++){ int i=i0+j; if(i<NN){ row_start[i]=run; run += cnt[i]; } }
  if(t==0) row_start[NN] = part[1023];
}

// place edges in CSR order AND gather edge_attr to CSR order (fused)
__global__ void k_place(const int* __restrict__ src, const int* __restrict__ tgt,
                        const float* __restrict__ ea,
                        const int* __restrict__ row_start, int* __restrict__ cur,
                        int* __restrict__ es_src, float* __restrict__ es_ea){
  int e = blockIdx.x*blockDim.x + threadIdx.x;
  if(e>=NE) return;
  int n = tgt[e];
  int pos = row_start[n] + atomicAdd(&cur[n],1);
  es_src[pos] = src[e];
  const float4* s = (const float4*)ea + (size_t)e*4;
  float4* d = (float4*)es_ea + (size_t)pos*4;
  d[0]=s[0]; d[1]=s[1]; d[2]=s[2]; d[3]=s[3];
}

// ---------------- H = relu(es_ea @ W1 + b1), CSR-ordered, E x 128 ----------------
// Persistent grid-stride (round 8): short-block kernels at 10-25k blocks undershoot
// occupancy ~2x vs eligibility (rounds 6/7) => dispatch turnover, not resources.
// Bonus: W1/b1 register tile hoisted out of the work loop (was reloaded per block).
__launch_bounds__(256, 4)
__global__ void k_hmlp(const float* __restrict__ es_ea, const float* __restrict__ W1,
                       const float* __restrict__ b1, float* __restrict__ H){
  const int pc = threadIdx.x & 31, er = threadIdx.x >> 5;
  float4 w1v[16];
  #pragma unroll
  for(int i=0;i<16;i++) w1v[i] = *(const float4*)&W1[i*128 + pc*4];
  const float4 bv = *(const float4*)&b1[pc*4];
  for(size_t e0 = (size_t)blockIdx.x*8; e0 < NE; e0 += (size_t)gridDim.x*8){
    const size_t e = e0 + er;
    float4 hv = bv;
    float eav[16];
    const float4* eap = (const float4*)(es_ea + e*16);
    #pragma unroll
    for(int q=0;q<4;q++){
      float4 v = eap[q];
      eav[q*4+0]=v.x; eav[q*4+1]=v.y; eav[q*4+2]=v.z; eav[q*4+3]=v.w;
    }
    #pragma unroll
    for(int i=0;i<16;i++){
      hv.x += eav[i]*w1v[i].x;
      hv.y += eav[i]*w1v[i].y;
      hv.z += eav[i]*w1v[i].z;
      hv.w += eav[i]*w1v[i].w;
    }
    hv.x = fmaxf(hv.x,0.f); hv.y = fmaxf(hv.y,0.f);
    hv.z = fmaxf(hv.z,0.f); hv.w = fmaxf(hv.w,0.f);
    *(float4*)&H[e*128 + pc*4] = hv;
  }
}

// ---------------- xbar[n,i] = mean over in-edges of x[src,i] ----------------
template<int IC>
__global__ void k_xbar(const float* __restrict__ x, const int* __restrict__ es_src,
                       const int* __restrict__ row_start, float* __restrict__ xbar){
  constexpr int TI = IC/16;
  const int wid = threadIdx.x>>6, lane = threadIdx.x&63;
  const int eg = lane>>4, ig = lane&15;
  for(int n0 = blockIdx.x*4; n0 < NN; n0 += gridDim.x*4){
    const int n = n0 + wid;
    const int a = row_start[n], b = row_start[n+1];
    float s[TI];
    #pragma unroll
    for(int u=0;u<TI;u++) s[u]=0.f;
    for(int e=a+eg; e<b; e+=4){
      int sn = es_src[e];
      #pragma unroll
      for(int u=0;u<TI;u++) s[u] += x[(size_t)sn*IC + ig*TI + u];
    }
    #pragma unroll
    for(int u=0;u<TI;u++){
      s[u] += __shfl_xor(s[u], 16, 64);
      s[u] += __shfl_xor(s[u], 32, 64);
    }
    if(eg==0){
      float dinv = 1.f/fmaxf((float)(b-a), 1.f);
      #pragma unroll
      for(int u=0;u<TI;u++) xbar[(size_t)n*IC + ig*TI + u] = s[u]*dinv;
    }
  }
}

// ---------------- fused NNConv layer: persistent blocks, wave-private scatter + k-split GEMM ----------------
// Round 8 package (see journal): persistence + BN=8 + KS-up + VGPR<=64.
//  - Persistent grid-stride work loop over items (nb,split): rounds 6/7 showed measured
//    occupancy ~2x below resource eligibility with 10-20k us-scale blocks (dispatch
//    turnover). Long-lived blocks keep CUs full; grid = NB (template) blocks total.
//  - BN=8: W2 L2-traffic per node halved vs BN=4 (round 7: doubling it ate the occupancy
//    win). KS raised instead to shrink S: L1 32KB, L2 24KB, L3 32KB -> 4-6 blocks/CU.
//  - VGPR<=64 target (m69 quantization: <=64 -> 8 waves/SIMD): scatter PF prefetch
//    dropped (neutral in rounds 2/3) and GEMM wv ping-pong dropped (its round-2 win was
//    latency hiding at 12 waves; 20-24 waves of TLP cover it). NEVER min-waves bounds
//    (rounds 4/5: squeezed VGPR to 40 + GB-scale scratch spill).
//  - Cross-wave combine via dead S: one part slice per split (k_epi SL=KS) -- required
//    for KS=8 to fit part, halves epi traffic, adds 2 barriers per item.
// No-spill check: FETCH ~85-105MB, WRITE ~20MB, VGPR<=64.
template<int IC, int OC, int PLEN, int KS, int BN, int PP, int TI, int OQ, int TO, int EB, int NB>
__launch_bounds__(256, 3)
__global__ void k_layer(const float* __restrict__ x_in, const float* __restrict__ H,
                        const int* __restrict__ es_src, const int* __restrict__ row_start,
                        const float* __restrict__ W2, float* __restrict__ part)
{
  constexpr int K    = PLEN*IC;
  constexpr int HV4  = PLEN/4;
  constexpr int XV   = IC/4;
  constexpr int NIW  = IC/TI;
  constexpr int NPW  = PLEN/PP;
  constexpr int G    = BN/4;
  constexpr int KQL  = 64/OQ;
  constexpr int TSPL = 4*KQL;
  constexpr int J    = (K/4)/TSPL;
  constexpr int NH4  = (EB*HV4 + 255)/256;   // hb staging chunks
  constexpr int NX4  = (EB*XV  + 255)/256;   // xs staging chunks
  constexpr int TOT  = (NN/BN)*KS;           // work items
  static_assert(NPW*NIW==64, "wave tile covers 64 lanes");
  static_assert(G*PP*TI <= 48, "spill-safe accumulator");
  static_assert(EB*(PLEN+IC) <= BN*K, "staging alias fits in S");
  static_assert((EB*HV4)%256==0, "hb tail must not round into xs region");
  static_assert(EB*PLEN/4 + NX4*256 <= BN*K/4, "xs tail rounding stays inside S");
  static_assert(OQ*TO==OC && (K/4)%TSPL==0, "gemm tiling");
  static_assert(3*BN*OC <= BN*K, "combine area fits in dead S");

  __shared__ __align__(16) float S[BN*K];
  __shared__ int rs_s[BN+1], ro[BN+1];

  float* hb = S;                 // EB*PLEN staged H slice
  float* xs = S + EB*PLEN;       // EB*IC staged x[src]

  const int tid = threadIdx.x;
  const int wid = tid>>6, lane = tid&63;
  const int pw = lane / NIW;
  const int iw = lane - pw*NIW;
  const int oq  = lane % OQ;
  const int kql = lane / OQ;
  const int o0  = oq*TO;

  const float4* H4 = (const float4*)H;
  const float4* x4 = (const float4*)x_in;

  #pragma unroll 1
  for(int it = blockIdx.x; it < TOT; it += NB){
    const int split = it % KS;
    const int nb = it / KS;
    const int n0 = nb*BN;
    const int p04 = split*HV4;

    if(tid<=BN) rs_s[tid] = row_start[n0+tid];
    __syncthreads();
    const int estart = rs_s[0], eend = rs_s[BN];

    float acc[G][PP][TI];
    #pragma unroll
    for(int g=0;g<G;g++)
      #pragma unroll
      for(int p=0;p<PP;p++)
        #pragma unroll
        for(int u=0;u<TI;u++) acc[g][p][u]=0.f;

    for(int bstart=estart; bstart<eend; bstart+=EB){
      const int ebc = min(EB, eend-bstart);
      if(tid<=BN){ int v = rs_s[tid]-bstart; ro[tid] = min(max(v,0), ebc); }
      const int hb_lim = ebc*HV4, xs_lim = ebc*XV;
      int sn_r[NX4];
      #pragma unroll
      for(int c=0;c<NX4;c++){
        int jc = min(tid + c*256, xs_lim-1);
        sn_r[c] = es_src[bstart + jc/XV];
      }
      #pragma unroll
      for(int c=0;c<NH4;c++){
        int j = tid + c*256;
        int jc = min(j, hb_lim-1);
        int e = jc/HV4, q = jc - e*HV4;
        gload_lds16<2>(H4 + (size_t)(bstart+e)*32 + p04 + q, ((float4*)hb) + j);
      }
      #pragma unroll
      for(int c=0;c<NX4;c++){
        int j = tid + c*256;
        int jc = min(j, xs_lim-1);
        int q = jc - (jc/XV)*XV;
        gload_lds16<0>(x4 + (size_t)sn_r[c]*XV + q, ((float4*)xs) + j);
      }
      __syncthreads();   // drains vmcnt (global_load_lds tracked there)
      // wave-private scatter (no PF: keeps scatter-phase VGPR low)
      #pragma unroll
      for(int g=0; g<G; g++){
        const int nl = wid*G + g;
        const int a = ro[nl], b = ro[nl+1];
        for(int e=a; e<b; e++){
          float hv[PP];
          #pragma unroll
          for(int p=0;p<PP;p++) hv[p] = hb[e*PLEN + pw*PP + p];
          float xv[TI];
          #pragma unroll
          for(int u=0;u<TI;u++) xv[u] = xs[e*IC + iw*TI + u];
          #pragma unroll
          for(int p=0;p<PP;p++)
            #pragma unroll
            for(int u=0;u<TI;u++) acc[g][p][u] += hv[p]*xv[u];
        }
      }
      __syncthreads();
    }

    // dump scaled S (staging area dead)
    #pragma unroll
    for(int g=0; g<G; g++){
      const int nl = wid*G + g;
      const float dv = 1.f/fmaxf((float)(rs_s[nl+1]-rs_s[nl]), 1.f);
      #pragma unroll
      for(int p=0;p<PP;p++)
        #pragma unroll
        for(int u=0;u<TI;u++)
          S[(nl*PLEN + pw*PP + p)*IC + iw*TI + u] = acc[g][p][u]*dv;
    }
    __syncthreads();

    // ---- GEMM: k-range split 4 waves x KQL lanes; coalesced W2; no ping-pong ----
    const float* W2b = W2 + (size_t)split*K*OC + o0;
    float outp[BN][TO];
    #pragma unroll
    for(int n=0;n<BN;n++)
      #pragma unroll
      for(int t=0;t<TO;t++) outp[n][t]=0.f;

    #pragma unroll 1
    for(int j=0;j<J;j++){
      const int k4 = j*TSPL + wid*KQL + kql;
      float wv[4][TO];
      #pragma unroll
      for(int r=0;r<4;r++){
        const float* wr = W2b + (size_t)(4*k4+r)*OC;
        if constexpr (TO==4){
          float4 a=*(const float4*)wr;
          wv[r][0]=a.x; wv[r][1]=a.y; wv[r][2]=a.z; wv[r][3]=a.w;
        } else if constexpr (TO==3){
          wv[r][0]=wr[0]; wv[r][1]=wr[1]; wv[r][2]=wr[2];
        } else {
          float2 a=*(const float2*)wr;
          wv[r][0]=a.x; wv[r][1]=a.y;
        }
      }
      #pragma unroll
      for(int n=0;n<BN;n++){
        float4 sv = *(const float4*)&S[n*K + 4*k4];
        #pragma unroll
        for(int t=0;t<TO;t++)
          outp[n][t] += sv.x*wv[0][t] + sv.y*wv[1][t] + sv.z*wv[2][t] + sv.w*wv[3][t];
      }
    }

    // intra-wave reduce over kql lanes
    #pragma unroll
    for(int m=OQ; m<64; m<<=1)
      #pragma unroll
      for(int n=0;n<BN;n++)
        #pragma unroll
        for(int t=0;t<TO;t++) outp[n][t] += __shfl_xor(outp[n][t], m, 64);

    // cross-wave combine through dead S: one part slice per split
    __syncthreads();   // all GEMM S-reads complete
    if(wid>0 && kql==0){
      #pragma unroll
      for(int n=0;n<BN;n++)
        #pragma unroll
        for(int t=0;t<TO;t++) S[((wid-1)*BN+n)*OC + o0 + t] = outp[n][t];
    }
    __syncthreads();
    if(wid==0 && kql==0){
      float* slice = part + (size_t)split*NN*OC;
      #pragma unroll
      for(int n=0;n<BN;n++){
        #pragma unroll
        for(int t=0;t<TO;t++){
          float v = outp[n][t];
          #pragma unroll
          for(int w2=0;w2<3;w2++) v += S[(w2*BN+n)*OC + o0 + t];
          outp[n][t] = v;
        }
        float* dst = slice + (size_t)(n0+n)*OC + o0;
        if constexpr (TO==4){
          *(float4*)dst = make_float4(outp[n][0],outp[n][1],outp[n][2],outp[n][3]);
        } else if constexpr (TO==3){
          dst[0]=outp[n][0]; dst[1]=outp[n][1]; dst[2]=outp[n][2];
        } else {
          *(float2*)dst = make_float2(outp[n][0],outp[n][1]);
        }
      }
    }
  }
}

// ---------------- epilogue: y = relu(sum_s part[s] + x@root + xbar@b2 + bias) ----------------
template<int IC, int OC, int SL>
__global__ void k_epi(const float* __restrict__ part, const float* __restrict__ x,
                      const float* __restrict__ xbar,
                      const float* __restrict__ root, const float* __restrict__ b2,
                      const float* __restrict__ bias, float* __restrict__ y)
{
  for(int idx = blockIdx.x*256 + threadIdx.x; idx < NN*OC; idx += gridDim.x*256){
    int n = idx/OC, o = idx - n*OC;
    float v = bias[o];
    #pragma unroll
    for(int s=0;s<SL;s++) v += part[(size_t)s*NN*OC + idx];
    #pragma unroll
    for(int i=0;i<IC;i++) v += x[(size_t)n*IC+i]*root[i*OC+o];
    #pragma unroll
    for(int i=0;i<IC;i++) v += xbar[(size_t)n*IC+i]*b2[i*OC+o];
    y[idx] = fmaxf(v, 0.f);
  }
}

// ---------------- set2set (2 steps) + final MLP, one wave per graph ----------------
__global__ void k_s2s(const float* __restrict__ xg, const int* __restrict__ batch,
  const float* __restrict__ Wih, const float* __restrict__ Whh,
  const float* __restrict__ bih, const float* __restrict__ bhh,
  const float* __restrict__ l1W, const float* __restrict__ l1b,
  const float* __restrict__ l2W, const float* __restrict__ l2b,
  const float* __restrict__ lfW, const float* __restrict__ lfb,
  float* __restrict__ out)
{
  int g = blockIdx.x, lane = threadIdx.x;
  __shared__ float hs[16], cs[16], qs[32], gs[64], rs[16];
  int r0 = lowerb(batch, NN, g);
  int r1 = lowerb(batch, NN, g+1);
  if(lane<16){ hs[lane]=0.f; cs[lane]=0.f; }
  if(lane<32) qs[lane]=0.f;
  __syncthreads();
  for(int step=0; step<2; step++){
    float gate = bih[lane] + bhh[lane];
    for(int k=0;k<32;k++) gate += qs[k]*Wih[lane*32+k];
    for(int k=0;k<16;k++) gate += hs[k]*Whh[lane*16+k];
    gs[lane] = gate;
    __syncthreads();
    if(lane<16){
      float ig = 1.f/(1.f+expf(-gs[lane]));
      float fg = 1.f/(1.f+expf(-gs[lane+16]));
      float gg = tanhf(gs[lane+32]);
      float og = 1.f/(1.f+expf(-gs[lane+48]));
      float cn = fg*cs[lane] + ig*gg;
      cs[lane] = cn;
      hs[lane] = og*tanhf(cn);
    }
    __syncthreads();
    float m = -1e30f;
    for(int n=r0+lane; n<r1; n+=64){
      float e=0.f;
      for(int k=0;k<16;k++) e += xg[n*16+k]*hs[k];
      m = fmaxf(m, e);
    }
    for(int d=1; d<64; d<<=1) m = fmaxf(m, __shfl_xor(m, d));
    float ssum = 0.f;
    float racc[16];
    #pragma unroll
    for(int k=0;k<16;k++) racc[k]=0.f;
    for(int n=r0+lane; n<r1; n+=64){
      float e=0.f, xv[16];
      #pragma unroll
      for(int k=0;k<16;k++){ xv[k]=xg[n*16+k]; e += xv[k]*hs[k]; }
      float a = expf(e - m);
      ssum += a;
      #pragma unroll
      for(int k=0;k<16;k++) racc[k] += a*xv[k];
    }
    for(int d=1; d<64; d<<=1) ssum += __shfl_xor(ssum, d);
    #pragma unroll
    for(int k=0;k<16;k++)
      for(int d=1; d<64; d<<=1) racc[k] += __shfl_xor(racc[k], d);
    ssum = fmaxf(ssum, 1e-16f);
    if(lane==0){
      #pragma unroll
      for(int k=0;k<16;k++) rs[k] = racc[k]/ssum;
    }
    __syncthreads();
    if(lane<16){ qs[lane]=hs[lane]; qs[16+lane]=rs[lane]; }
    __syncthreads();
  }
  if(lane<16){
    float v = l1b[lane];
    for(int k=0;k<32;k++) v += qs[k]*l1W[k*16+lane];
    gs[lane] = fmaxf(v,0.f);
  }
  __syncthreads();
  if(lane<8){
    float v = l2b[lane];
    for(int k=0;k<16;k++) v += gs[k]*l2W[k*8+lane];
    gs[32+lane] = fmaxf(v,0.f);
  }
  __syncthreads();
  if(lane==0){
    float v = lfb[0];
    for(int k=0;k<8;k++) v += gs[32+k]*lfW[k];
    out[g] = v;
  }
}

extern "C" void kernel_launch(void* const* d_in, const int* in_sizes, int n_in,
                              void* d_out, int out_size, void* d_ws, size_t ws_size,
                              hipStream_t stream) {
  const float* x0   = (const float*)d_in[0];
  const int*   ei   = (const int*)d_in[1];
  const float* ea   = (const float*)d_in[2];
  const int*   batch= (const int*)d_in[3];
  const float* c1W1 = (const float*)d_in[4];  const float* c1b1 = (const float*)d_in[5];
  const float* c1W2 = (const float*)d_in[6];  const float* c1b2 = (const float*)d_in[7];
  const float* c1rt = (const float*)d_in[8];  const float* c1bs = (const float*)d_in[9];
  const float* c2W1 = (const float*)d_in[10]; const float* c2b1 = (const float*)d_in[11];
  const float* c2W2 = (const float*)d_in[12]; const float* c2b2 = (const float*)d_in[13];
  const float* c2rt = (const float*)d_in[14]; const float* c2bs = (const float*)d_in[15];
  const float* c3W1 = (const float*)d_in[16]; const float* c3b1 = (const float*)d_in[17];
  const float* c3W2 = (const float*)d_in[18]; const float* c3b2 = (const float*)d_in[19];
  const float* c3rt = (const float*)d_in[20]; const float* c3bs = (const float*)d_in[21];
  const float* Wih  = (const float*)d_in[22]; const float* Whh  = (const float*)d_in[23];
  const float* bih  = (const float*)d_in[24]; const float* bhh  = (const float*)d_in[25];
  const float* l1W  = (const float*)d_in[26]; const float* l1b  = (const float*)d_in[27];
  const float* l2W  = (const float*)d_in[28]; const float* l2b  = (const float*)d_in[29];
  const float* lfW  = (const float*)d_in[30]; const float* lfb  = (const float*)d_in[31];
  float* out = (float*)d_out;

  const int* src = ei;
  const int* tgt = ei + NE;

  // workspace carve (~190 MB)
  char* w = (char*)d_ws;
  auto carve = [&](size_t bytes)->void*{ void* p = (void*)w; w += (bytes + 255) & ~(size_t)255; return p; };
  int*   row_start = (int*)carve((NN+1)*sizeof(int));
  int*   cur       = (int*)carve(NN*sizeof(int));
  int*   es_src    = (int*)carve(NE*sizeof(int));
  float* es_ea     = (float*)carve((size_t)NE*16*sizeof(float));
  float* Hbuf      = (float*)carve((size_t)NE*128*sizeof(float));
  float* xbar      = (float*)carve((size_t)NN*48*sizeof(float));
  float* y1   = (float*)carve((size_t)NN*48*sizeof(float));
  float* y2   = (float*)carve((size_t)NN*32*sizeof(float));
  float* y3   = (float*)carve((size_t)NN*16*sizeof(float));
  float* part = (float*)carve((size_t)16*NN*48*sizeof(float)); // up to 16 slices

  // ---- CSR by tgt (+ fused ea gather)
  hipMemsetAsync(cur, 0, NN*sizeof(int), stream);
  k_count<<<(NE+255)/256, 256, 0, stream>>>(tgt, cur);
  k_scan<<<1, 1024, 0, stream>>>(cur, row_start);
  hipMemsetAsync(cur, 0, NN*sizeof(int), stream);
  k_place<<<(NE+255)/256, 256, 0, stream>>>(src, tgt, ea, row_start, cur, es_src, es_ea);

  // ---- layer 1: IC=16 OC=48 | PLEN=64 KS=2 BN=8 PP=4 TI=4 | OQ=16 TO=3 | EB=96, S=32KB, slices=2
  k_hmlp<<<2048, 256, 0, stream>>>(es_ea, c1W1, c1b1, Hbuf);
  k_xbar<16><<<2048, 256, 0, stream>>>(x0, es_src, row_start, xbar);
  k_layer<16,48,64,2,8,4,4,16,3,96,2048><<<2048, 256, 0, stream>>>(x0, Hbuf, es_src, row_start, c1W2, part);
  k_epi<16,48,2><<<2048, 256, 0, stream>>>(part, x0, xbar, c1rt, c1b2, c1bs, y1);

  // ---- layer 2: IC=48 OC=32 | PLEN=16 KS=8 BN=8 PP=4 TI=3 | OQ=8 TO=4 | EB=64, S=24KB, slices=8
  k_hmlp<<<2048, 256, 0, stream>>>(es_ea, c2W1, c2b1, Hbuf);
  k_xbar<48><<<2048, 256, 0, stream>>>(y1, es_src, row_start, xbar);
  k_layer<48,32,16,8,8,4,3,8,4,64,3072><<<3072, 256, 0, stream>>>(y1, Hbuf, es_src, row_start, c2W2, part);
  k_epi<48,32,8><<<2048, 256, 0, stream>>>(part, y1, xbar, c2rt, c2b2, c2bs, y2);

  // ---- layer 3: IC=32 OC=16 | PLEN=32 KS=4 BN=8 PP=4 TI=4 | OQ=4 TO=4 | EB=96, S=32KB, slices=4
  k_hmlp<<<2048, 256, 0, stream>>>(es_ea, c3W1, c3b1, Hbuf);
  k_xbar<32><<<2048, 256, 0, stream>>>(y2, es_src, row_start, xbar);
  k_layer<32,16,32,4,8,4,4,4,4,96,2048><<<2048, 256, 0, stream>>>(y2, Hbuf, es_src, row_start, c3W2, part);
  k_epi<32,16,4><<<2048, 256, 0, stream>>>(part, y2, xbar, c3rt, c3b2, c3bs, y3);

  // ---- set2set + MLP head
  k_s2s<<<NG, 64, 0, stream>>>(y3, batch, Wih, Whh, bih, bhh, l1W, l1b, l2W, l2b, lfW, lfb, out);
}